// Round 1
// baseline (6520.719 us; speedup 1.0000x reference)
//
#include <hip/hip_runtime.h>
#include <hip/hip_bf16.h>
#include <math.h>

#define NB 64
#define NBT 16
#define IMG 224
#define PATCHSZ 16
#define CIN 3
#define EMB 192
#define NHEADS 3
#define DEPTH 12
#define MLPD (4*EMB)
#define NPATCH 196
#define NTOK 197
#define M_TOK (NB*NTOK)      // 12608
#define M_PATCH (NB*NPATCH)  // 12544
#define SAT_H 8
#define SAT_DK 32
#define SAT_D 256

// ---------------------------------------------------------------- stats
__global__ __launch_bounds__(256) void stats_kernel(const float* __restrict__ xg,
    const float* __restrict__ per_li, const float* __restrict__ per_li_var,
    int* __restrict__ idx_out)
{
    int s = blockIdx.x;
    const float* row = xg + (size_t)s * (IMG*IMG);
    double lsum = 0.0, lsq = 0.0;
    for (int i = threadIdx.x; i < IMG*IMG; i += 256) {
        double v = (double)row[i]; lsum += v; lsq += v*v;
    }
    __shared__ double ssum[256], ssq[256];
    ssum[threadIdx.x] = lsum; ssq[threadIdx.x] = lsq;
    __syncthreads();
    for (int st = 128; st > 0; st >>= 1) {
        if (threadIdx.x < st) { ssum[threadIdx.x] += ssum[threadIdx.x+st]; ssq[threadIdx.x] += ssq[threadIdx.x+st]; }
        __syncthreads();
    }
    if (threadIdx.x == 0) {
        double n = (double)(IMG*IMG);
        double mean = ssum[0] / n;
        double var  = (ssq[0] - n*mean*mean) / (n - 1.0);
        int i1 = 0, i2 = 0;
        for (int j = 0; j < 15; j++) {
            if ((double)per_li[j] < mean) i1++;
            if ((double)per_li_var[j] < var) i2++;
        }
        idx_out[s] = i1; idx_out[16 + s] = i2;
    }
}

// ---------------------------------------------------------------- im2col
__global__ __launch_bounds__(256) void im2col_kernel(const float* __restrict__ x, float* __restrict__ out)
{
    int e = blockIdx.x*256 + threadIdx.x;
    if (e >= M_PATCH*768) return;
    int row = e / 768, col = e % 768;
    int b = row / NPATCH, p = row % NPATCH;
    int py = p / 14, px = p % 14;
    int c = col >> 8, r8 = col & 255;
    int i = r8 >> 4, j = r8 & 15;
    out[e] = x[(((size_t)b*CIN + c)*IMG + py*16 + i)*IMG + px*16 + j];
}

// ---------------------------------------------------------------- cls row
__global__ void cls_kernel(const float* __restrict__ cls, const float* __restrict__ pos, float* __restrict__ tok)
{
    int i = blockIdx.x*256 + threadIdx.x;
    if (i >= NB*EMB) return;
    int b = i / EMB, e = i % EMB;
    tok[(size_t)(b*NTOK)*EMB + e] = cls[e] + pos[e];
}

// ---------------------------------------------------------------- generic fp32 GEMM
// C[M][ldc] = A[M][K] @ W + epilogue.  WT: W is [N][K] (row per output col), else [K][N].
// EPI: 0 none, 1 +bias*bias_scale, 2 +bias + C (in-place residual), 3 gelu(acc+bias), 4 patch-embed scatter
template<bool WT, int EPI>
__global__ __launch_bounds__(256) void gemm_kernel(
    const float* __restrict__ A, const float* __restrict__ W,
    const float* __restrict__ bias, const float* __restrict__ aux,
    float* __restrict__ C, int M, int N, int K, int ldc, float bias_scale)
{
    __shared__ float As[16][68];
    __shared__ float Ws[16][68];
    int tid = threadIdx.x;
    int tx = tid & 15, ty = tid >> 4;
    int n0 = blockIdx.x*64, m0 = blockIdx.y*64;
    float acc[4][4] = {};
    int la_r = tid >> 2;          // 0..63
    int la_k = (tid & 3) * 4;     // 0,4,8,12

    for (int k0 = 0; k0 < K; k0 += 16) {
        float4 av = *(const float4*)(A + (size_t)(m0 + la_r)*K + k0 + la_k);
        As[la_k+0][la_r]=av.x; As[la_k+1][la_r]=av.y; As[la_k+2][la_r]=av.z; As[la_k+3][la_r]=av.w;
        if (!WT) {
            int wk = tid >> 4;
            int wn = (tid & 15) * 4;
            float4 wv = *(const float4*)(W + (size_t)(k0 + wk)*N + n0 + wn);
            *(float4*)&Ws[wk][wn] = wv;
        } else {
            float4 wv = *(const float4*)(W + (size_t)(n0 + la_r)*K + k0 + la_k);
            Ws[la_k+0][la_r]=wv.x; Ws[la_k+1][la_r]=wv.y; Ws[la_k+2][la_r]=wv.z; Ws[la_k+3][la_r]=wv.w;
        }
        __syncthreads();
        #pragma unroll
        for (int kk = 0; kk < 16; kk++) {
            float4 a = *(const float4*)&As[kk][ty*4];
            float4 b = *(const float4*)&Ws[kk][tx*4];
            float ar[4] = {a.x,a.y,a.z,a.w};
            float br[4] = {b.x,b.y,b.z,b.w};
            #pragma unroll
            for (int i = 0; i < 4; i++)
                #pragma unroll
                for (int j = 0; j < 4; j++) acc[i][j] += ar[i]*br[j];
        }
        __syncthreads();
    }
    #pragma unroll
    for (int i = 0; i < 4; i++) {
        int row = m0 + ty*4 + i;
        #pragma unroll
        for (int j = 0; j < 4; j++) {
            int col = n0 + tx*4 + j;
            float v = acc[i][j];
            if constexpr (EPI == 4) {
                int b_ = row / NPATCH, p = row % NPATCH;
                int orow = b_*NTOK + 1 + p;
                C[(size_t)orow*EMB + col] = v + bias[col] + aux[(size_t)(1+p)*EMB + col];
            } else {
                if constexpr (EPI == 1) v += bias[col]*bias_scale;
                if constexpr (EPI == 2) v = C[(size_t)row*ldc + col] + v + bias[col];
                if constexpr (EPI == 3) { v += bias[col]; v = 0.5f*v*(1.0f + erff(v*0.70710678118654752f)); }
                C[(size_t)row*ldc + col] = v;
            }
        }
    }
}

// ---------------------------------------------------------------- SAT per-sample rows
// proj[s][6][256]: 0=q_ele 1=k_ele 2=v_ele 3=q_vele 4=k_vele 5=v_vele   sconst[s][h][4]: S11,S12,S21,S22 (scaled)
__global__ __launch_bounds__(256) void sat_rows_kernel(
    const float* __restrict__ eleva, const float* __restrict__ eleva_var,
    const float* __restrict__ wq, const float* __restrict__ bq,
    const float* __restrict__ wk, const float* __restrict__ bk,
    const float* __restrict__ wv, const float* __restrict__ bv,
    const int* __restrict__ idx, float* __restrict__ proj, float* __restrict__ sconst)
{
    int s = blockIdx.x;
    __shared__ float ev[2][EMB];
    __shared__ float pr[6][SAT_D];
    int t = threadIdx.x;
    for (int i = t; i < 2*EMB; i += 256) {
        if (i < EMB) ev[0][i] = eleva[(size_t)idx[s]*EMB + i];
        else         ev[1][i-EMB] = eleva_var[(size_t)idx[16+s]*EMB + (i-EMB)];
    }
    __syncthreads();
    for (int j = 0; j < 6; j++) {
        const float* vec = ev[(j >= 3) ? 1 : 0];
        const float* Wm = (j%3 == 0) ? wq : ((j%3 == 1) ? wk : wv);
        const float* bm = (j%3 == 0) ? bq : ((j%3 == 1) ? bk : bv);
        float accv = bm[t];
        for (int k = 0; k < EMB; k++) accv += vec[k]*Wm[(size_t)k*SAT_D + t];
        pr[j][t] = accv;
        proj[((size_t)s*6 + j)*SAT_D + t] = accv;
    }
    __syncthreads();
    if (t < 32) {
        int h = t >> 2, c = t & 3;
        const float* qv = pr[(c < 2) ? 0 : 3];
        const float* kv = pr[((c & 1) == 0) ? 1 : 4];
        float d = 0.f;
        for (int x = 0; x < SAT_DK; x++) d += qv[h*32+x]*kv[h*32+x];
        sconst[((size_t)s*8 + h)*4 + c] = d * 0.17677669529663687f;
    }
}

// ---------------------------------------------------------------- SAT main (per token)
__global__ __launch_bounds__(256) void sat_attn_kernel(
    const float* __restrict__ qkv0, const float* __restrict__ proj,
    const float* __restrict__ sconst, float* __restrict__ osum)
{
    int b = blockIdx.x;
    int s = b & 15;
    __shared__ float pr[6][SAT_D];
    __shared__ float sc[8][4];
    for (int i = threadIdx.x; i < 6*SAT_D; i += 256) pr[i >> 8][i & 255] = proj[(size_t)s*6*SAT_D + i];
    if (threadIdx.x < 32) sc[threadIdx.x >> 2][threadIdx.x & 3] = sconst[(size_t)s*32 + threadIdx.x];
    __syncthreads();
    int t = threadIdx.x;
    if (t >= NTOK) return;
    size_t m = (size_t)b*NTOK + t;
    const float* q0 = qkv0 + m*768;
    const float* k0 = q0 + 256;
    const float* v0 = q0 + 512;
    const float inv = 0.17677669529663687f;
    for (int h = 0; h < SAT_H; h++) {
        int d0 = h*32;
        float S00=0,S01=0,S02=0,S10=0,S20=0;
        #pragma unroll 8
        for (int d = 0; d < 32; d++) {
            float qv = q0[d0+d], kv = k0[d0+d];
            S00 += qv*kv;
            S01 += qv*pr[1][d0+d];
            S02 += qv*pr[4][d0+d];
            S10 += pr[0][d0+d]*kv;
            S20 += pr[3][d0+d]*kv;
        }
        S00*=inv; S01*=inv; S02*=inv; S10*=inv; S20*=inv;
        float al=0.f, be=0.f, ga=0.f;
        {
            float mx = fmaxf(S00, fmaxf(S01, S02));
            float e0 = expf(S00-mx), e1 = expf(S01-mx), e2 = expf(S02-mx);
            float is = 1.0f/(e0+e1+e2); al += e0*is; be += e1*is; ga += e2*is;
        }
        {
            float a1 = sc[h][0], a2 = sc[h][1];
            float mx = fmaxf(S10, fmaxf(a1, a2));
            float e0 = expf(S10-mx), e1 = expf(a1-mx), e2 = expf(a2-mx);
            float is = 1.0f/(e0+e1+e2); al += e0*is; be += e1*is; ga += e2*is;
        }
        {
            float a1 = sc[h][2], a2 = sc[h][3];
            float mx = fmaxf(S20, fmaxf(a1, a2));
            float e0 = expf(S20-mx), e1 = expf(a1-mx), e2 = expf(a2-mx);
            float is = 1.0f/(e0+e1+e2); al += e0*is; be += e1*is; ga += e2*is;
        }
        #pragma unroll 8
        for (int d = 0; d < 32; d++)
            osum[m*SAT_D + d0 + d] = al*v0[d0+d] + be*pr[2][d0+d] + ga*pr[5][d0+d];
    }
}

// ---------------------------------------------------------------- ViT attention, block per (b, head)
__global__ __launch_bounds__(256) void vit_attn_kernel(
    const float* __restrict__ qkv, float* __restrict__ hout)
{
    int b = blockIdx.x / NHEADS, hd = blockIdx.x % NHEADS;
    __shared__ __hip_bfloat16 Kp[NTOK][66];
    __shared__ __hip_bfloat16 Vp[NTOK][66];
    __shared__ float attL[4][256];
    const float* base = qkv + (size_t)b*NTOK*576;
    for (int i = threadIdx.x; i < NTOK*64; i += 256) {
        int t = i >> 6, d = i & 63;
        Kp[t][d] = __float2bfloat16(base[(size_t)t*576 + 192 + hd*64 + d]);
        Vp[t][d] = __float2bfloat16(base[(size_t)t*576 + 384 + hd*64 + d]);
    }
    __syncthreads();
    int wave = threadIdx.x >> 6, lane = threadIdx.x & 63;
    for (int t = wave; t < NTOK; t += 4) {
        const float* qrow = base + (size_t)t*576 + hd*64;
        float s0=0.f, s1=0.f, s2=0.f, s3=0.f;
        for (int d = 0; d < 64; d++) {
            float qd = qrow[d];
            s0 += qd * __bfloat162float(Kp[lane][d]);
            s1 += qd * __bfloat162float(Kp[lane+64][d]);
            s2 += qd * __bfloat162float(Kp[lane+128][d]);
            s3 += qd * __bfloat162float(Kp[lane+192][d]);   // OOB rows land in Vp's LDS; masked below
        }
        const float scale = 0.125f;
        s0 *= scale; s1 *= scale; s2 *= scale;
        s3 = (lane < NTOK-192) ? s3*scale : -1e30f;
        float mx = fmaxf(fmaxf(s0,s1), fmaxf(s2,s3));
        for (int o = 32; o > 0; o >>= 1) mx = fmaxf(mx, __shfl_xor(mx, o));
        float e0 = expf(s0-mx), e1 = expf(s1-mx), e2 = expf(s2-mx);
        float e3 = (lane < NTOK-192) ? expf(s3-mx) : 0.0f;
        float sm = e0+e1+e2+e3;
        for (int o = 32; o > 0; o >>= 1) sm += __shfl_xor(sm, o);
        float isv = 1.0f/sm;
        attL[wave][lane]      = e0*isv;
        attL[wave][lane+64]   = e1*isv;
        attL[wave][lane+128]  = e2*isv;
        attL[wave][lane+192]  = e3*isv;
        float o_ = 0.f;
        for (int k = 0; k < NTOK; k++) o_ += attL[wave][k] * __bfloat162float(Vp[k][lane]);
        hout[((size_t)b*NTOK + t)*EMB + hd*64 + lane] = o_;
    }
}

// ---------------------------------------------------------------- LayerNorm, 4 rows/block
__global__ __launch_bounds__(256) void ln_kernel(const float* __restrict__ in,
    const float* __restrict__ w, const float* __restrict__ b_, float* __restrict__ out, int nrows)
{
    int r = blockIdx.x*4 + (threadIdx.x >> 6);
    int lane = threadIdx.x & 63;
    if (r >= nrows) return;
    const float* x = in + (size_t)r*EMB;
    float x0 = x[lane], x1 = x[lane+64], x2 = x[lane+128];
    float s = x0+x1+x2;
    for (int o = 32; o > 0; o >>= 1) s += __shfl_xor(s, o);
    float mu = s * (1.0f/EMB);
    float d0 = x0-mu, d1 = x1-mu, d2 = x2-mu;
    float ss = d0*d0 + d1*d1 + d2*d2;
    for (int o = 32; o > 0; o >>= 1) ss += __shfl_xor(ss, o);
    float rs = rsqrtf(ss*(1.0f/EMB) + 1e-5f);
    float* y = out + (size_t)r*EMB;
    y[lane]     = d0*rs*w[lane]     + b_[lane];
    y[lane+64]  = d1*rs*w[lane+64]  + b_[lane+64];
    y[lane+128] = d2*rs*w[lane+128] + b_[lane+128];
}

// ---------------------------------------------------------------- final LN on t=0 rows only
__global__ __launch_bounds__(64) void final_ln_kernel(const float* __restrict__ tok,
    const float* __restrict__ w, const float* __restrict__ b_, float* __restrict__ out)
{
    int b = blockIdx.x, lane = threadIdx.x;
    const float* x = tok + (size_t)b*NTOK*EMB;
    float x0 = x[lane], x1 = x[lane+64], x2 = x[lane+128];
    float s = x0+x1+x2;
    for (int o = 32; o > 0; o >>= 1) s += __shfl_xor(s, o);
    float mu = s * (1.0f/EMB);
    float d0 = x0-mu, d1 = x1-mu, d2 = x2-mu;
    float ss = d0*d0 + d1*d1 + d2*d2;
    for (int o = 32; o > 0; o >>= 1) ss += __shfl_xor(ss, o);
    float rs = rsqrtf(ss*(1.0f/EMB) + 1e-5f);
    out[(size_t)b*EMB + lane]     = d0*rs*w[lane]     + b_[lane];
    out[(size_t)b*EMB + lane+64]  = d1*rs*w[lane+64]  + b_[lane+64];
    out[(size_t)b*EMB + lane+128] = d2*rs*w[lane+128] + b_[lane+128];
}

// ---------------------------------------------------------------- launch
extern "C" void kernel_launch(void* const* d_in, const int* in_sizes, int n_in,
                              void* d_out, int out_size, void* d_ws, size_t ws_size,
                              hipStream_t stream)
{
    const float* x          = (const float*)d_in[0];
    const float* xg         = (const float*)d_in[1];
    const float* per_li     = (const float*)d_in[2];
    const float* per_li_var = (const float*)d_in[3];
    const float* patch_w    = (const float*)d_in[4];
    const float* patch_b    = (const float*)d_in[5];
    const float* cls_token  = (const float*)d_in[6];
    const float* pos_embed  = (const float*)d_in[7];
    const float* eleva      = (const float*)d_in[8];
    const float* eleva_var  = (const float*)d_in[9];
    const float* sat_wq     = (const float*)d_in[10];
    const float* sat_bq     = (const float*)d_in[11];
    const float* sat_wk     = (const float*)d_in[12];
    const float* sat_bk     = (const float*)d_in[13];
    const float* sat_wv     = (const float*)d_in[14];
    const float* sat_bv     = (const float*)d_in[15];
    const float* sat_wo     = (const float*)d_in[16];
    const float* sat_bo     = (const float*)d_in[17];
    const float* ln1_w      = (const float*)d_in[18];
    const float* ln1_b      = (const float*)d_in[19];
    const float* qkv_w      = (const float*)d_in[20];
    const float* proj_w     = (const float*)d_in[21];
    const float* proj_b     = (const float*)d_in[22];
    const float* ln2_w      = (const float*)d_in[23];
    const float* ln2_b      = (const float*)d_in[24];
    const float* fc1_w      = (const float*)d_in[25];
    const float* fc1_b      = (const float*)d_in[26];
    const float* fc2_w      = (const float*)d_in[27];
    const float* fc2_b      = (const float*)d_in[28];
    const float* lnf_w      = (const float*)d_in[29];
    const float* lnf_b      = (const float*)d_in[30];
    float* out = (float*)d_out;

    float* ws    = (float*)d_ws;
    float* tok   = ws;                                   // 12608*192
    float* hbuf  = tok  + (size_t)M_TOK*EMB;             // 12608*192
    float* qkvb  = hbuf + (size_t)M_TOK*EMB;             // 12608*768 (also im2col / mlp-hidden)
    float* osum  = qkvb + (size_t)M_TOK*768;             // 12608*256
    float* projb = osum + (size_t)M_TOK*SAT_D;           // 16*6*256
    float* sconst= projb + 16*6*SAT_D;                   // 16*32
    int*   idxb  = (int*)(sconst + 16*32);               // 32 ints

    // elevation stats + bucketing
    stats_kernel<<<16, 256, 0, stream>>>(xg, per_li, per_li_var, idxb);
    // patch embed: im2col -> GEMM with pos-embed scatter epilogue
    im2col_kernel<<<(M_PATCH*768 + 255)/256, 256, 0, stream>>>(x, qkvb);
    gemm_kernel<true,4><<<dim3(EMB/64, M_PATCH/64), 256, 0, stream>>>(
        qkvb, patch_w, patch_b, pos_embed, tok, M_PATCH, EMB, 768, EMB, 1.0f);
    cls_kernel<<<(NB*EMB + 255)/256, 256, 0, stream>>>(cls_token, pos_embed, tok);
    // SAT: per-sample rows, token projections, tiny attention, output proj (bias*3, replaces tok)
    sat_rows_kernel<<<16, 256, 0, stream>>>(eleva, eleva_var, sat_wq, sat_bq, sat_wk, sat_bk,
                                            sat_wv, sat_bv, idxb, projb, sconst);
    gemm_kernel<false,1><<<dim3(SAT_D/64, M_TOK/64), 256, 0, stream>>>(
        tok, sat_wq, sat_bq, nullptr, qkvb + 0,   M_TOK, SAT_D, EMB, 768, 1.0f);
    gemm_kernel<false,1><<<dim3(SAT_D/64, M_TOK/64), 256, 0, stream>>>(
        tok, sat_wk, sat_bk, nullptr, qkvb + 256, M_TOK, SAT_D, EMB, 768, 1.0f);
    gemm_kernel<false,1><<<dim3(SAT_D/64, M_TOK/64), 256, 0, stream>>>(
        tok, sat_wv, sat_bv, nullptr, qkvb + 512, M_TOK, SAT_D, EMB, 768, 1.0f);
    sat_attn_kernel<<<NB, 256, 0, stream>>>(qkvb, projb, sconst, osum);
    gemm_kernel<false,1><<<dim3(EMB/64, M_TOK/64), 256, 0, stream>>>(
        osum, sat_wo, sat_bo, nullptr, tok, M_TOK, EMB, SAT_D, EMB, 3.0f);
    // ViT blocks
    for (int i = 0; i < DEPTH; i++) {
        ln_kernel<<<M_TOK/4, 256, 0, stream>>>(tok, ln1_w + i*EMB, ln1_b + i*EMB, hbuf, M_TOK);
        gemm_kernel<false,0><<<dim3(576/64, M_TOK/64), 256, 0, stream>>>(
            hbuf, qkv_w + (size_t)i*EMB*576, nullptr, nullptr, qkvb, M_TOK, 576, EMB, 576, 1.0f);
        vit_attn_kernel<<<NB*NHEADS, 256, 0, stream>>>(qkvb, hbuf);
        gemm_kernel<false,2><<<dim3(EMB/64, M_TOK/64), 256, 0, stream>>>(
            hbuf, proj_w + (size_t)i*EMB*EMB, proj_b + i*EMB, nullptr, tok, M_TOK, EMB, EMB, EMB, 1.0f);
        ln_kernel<<<M_TOK/4, 256, 0, stream>>>(tok, ln2_w + i*EMB, ln2_b + i*EMB, hbuf, M_TOK);
        gemm_kernel<false,3><<<dim3(MLPD/64, M_TOK/64), 256, 0, stream>>>(
            hbuf, fc1_w + (size_t)i*EMB*MLPD, fc1_b + i*MLPD, nullptr, qkvb, M_TOK, MLPD, EMB, MLPD, 1.0f);
        gemm_kernel<false,2><<<dim3(EMB/64, M_TOK/64), 256, 0, stream>>>(
            qkvb, fc2_w + (size_t)i*MLPD*EMB, fc2_b + i*EMB, nullptr, tok, M_TOK, EMB, MLPD, EMB, 1.0f);
    }
    final_ln_kernel<<<NB, 64, 0, stream>>>(tok, lnf_w, lnf_b, out);
}

// Round 2
// 4306.023 us; speedup vs baseline: 1.5143x; 1.5143x over previous
//
#include <hip/hip_runtime.h>
#include <hip/hip_bf16.h>
#include <math.h>

#define NB 64
#define NBT 16
#define IMG 224
#define PATCHSZ 16
#define CIN 3
#define EMB 192
#define NHEADS 3
#define DEPTH 12
#define MLPD (4*EMB)
#define NPATCH 196
#define NTOK 197
#define M_TOK (NB*NTOK)      // 12608
#define M_PATCH (NB*NPATCH)  // 12544
#define SAT_H 8
#define SAT_DK 32
#define SAT_D 256

// ---------------------------------------------------------------- stats
__global__ __launch_bounds__(256) void stats_kernel(const float* __restrict__ xg,
    const float* __restrict__ per_li, const float* __restrict__ per_li_var,
    int* __restrict__ idx_out)
{
    int s = blockIdx.x;
    const float* row = xg + (size_t)s * (IMG*IMG);
    double lsum = 0.0, lsq = 0.0;
    for (int i = threadIdx.x; i < IMG*IMG; i += 256) {
        double v = (double)row[i]; lsum += v; lsq += v*v;
    }
    __shared__ double ssum[256], ssq[256];
    ssum[threadIdx.x] = lsum; ssq[threadIdx.x] = lsq;
    __syncthreads();
    for (int st = 128; st > 0; st >>= 1) {
        if (threadIdx.x < st) { ssum[threadIdx.x] += ssum[threadIdx.x+st]; ssq[threadIdx.x] += ssq[threadIdx.x+st]; }
        __syncthreads();
    }
    if (threadIdx.x == 0) {
        double n = (double)(IMG*IMG);
        double mean = ssum[0] / n;
        double var  = (ssq[0] - n*mean*mean) / (n - 1.0);
        int i1 = 0, i2 = 0;
        for (int j = 0; j < 15; j++) {
            if ((double)per_li[j] < mean) i1++;
            if ((double)per_li_var[j] < var) i2++;
        }
        idx_out[s] = i1; idx_out[16 + s] = i2;
    }
}

// ---------------------------------------------------------------- im2col
__global__ __launch_bounds__(256) void im2col_kernel(const float* __restrict__ x, float* __restrict__ out)
{
    int e = blockIdx.x*256 + threadIdx.x;
    if (e >= M_PATCH*768) return;
    int row = e / 768, col = e % 768;
    int b = row / NPATCH, p = row % NPATCH;
    int py = p / 14, px = p % 14;
    int c = col >> 8, r8 = col & 255;
    int i = r8 >> 4, j = r8 & 15;
    out[e] = x[(((size_t)b*CIN + c)*IMG + py*16 + i)*IMG + px*16 + j];
}

// ---------------------------------------------------------------- cls row
__global__ void cls_kernel(const float* __restrict__ cls, const float* __restrict__ pos, float* __restrict__ tok)
{
    int i = blockIdx.x*256 + threadIdx.x;
    if (i >= NB*EMB) return;
    int b = i / EMB, e = i % EMB;
    tok[(size_t)(b*NTOK)*EMB + e] = cls[e] + pos[e];
}

// ---------------------------------------------------------------- generic fp32 GEMM
// C[M][ldc] = A[M][K] @ W + epilogue.  WT: W is [N][K] (row per output col), else [K][N].
// EPI: 0 none, 1 +bias*bias_scale, 2 +bias + C (in-place residual), 3 gelu(acc+bias), 4 patch-embed scatter
template<bool WT, int EPI>
__global__ __launch_bounds__(256) void gemm_kernel(
    const float* __restrict__ A, const float* __restrict__ W,
    const float* __restrict__ bias, const float* __restrict__ aux,
    float* __restrict__ C, int M, int N, int K, int ldc, float bias_scale)
{
    __shared__ float As[16][68];
    __shared__ float Ws[16][68];
    int tid = threadIdx.x;
    int tx = tid & 15, ty = tid >> 4;
    int n0 = blockIdx.x*64, m0 = blockIdx.y*64;
    float acc[4][4] = {};
    int la_r = tid >> 2;          // 0..63
    int la_k = (tid & 3) * 4;     // 0,4,8,12

    for (int k0 = 0; k0 < K; k0 += 16) {
        float4 av = *(const float4*)(A + (size_t)(m0 + la_r)*K + k0 + la_k);
        As[la_k+0][la_r]=av.x; As[la_k+1][la_r]=av.y; As[la_k+2][la_r]=av.z; As[la_k+3][la_r]=av.w;
        if (!WT) {
            int wk = tid >> 4;
            int wn = (tid & 15) * 4;
            float4 wv = *(const float4*)(W + (size_t)(k0 + wk)*N + n0 + wn);
            *(float4*)&Ws[wk][wn] = wv;
        } else {
            float4 wv = *(const float4*)(W + (size_t)(n0 + la_r)*K + k0 + la_k);
            Ws[la_k+0][la_r]=wv.x; Ws[la_k+1][la_r]=wv.y; Ws[la_k+2][la_r]=wv.z; Ws[la_k+3][la_r]=wv.w;
        }
        __syncthreads();
        #pragma unroll
        for (int kk = 0; kk < 16; kk++) {
            float4 a = *(const float4*)&As[kk][ty*4];
            float4 b = *(const float4*)&Ws[kk][tx*4];
            float ar[4] = {a.x,a.y,a.z,a.w};
            float br[4] = {b.x,b.y,b.z,b.w};
            #pragma unroll
            for (int i = 0; i < 4; i++)
                #pragma unroll
                for (int j = 0; j < 4; j++) acc[i][j] += ar[i]*br[j];
        }
        __syncthreads();
    }
    #pragma unroll
    for (int i = 0; i < 4; i++) {
        int row = m0 + ty*4 + i;
        #pragma unroll
        for (int j = 0; j < 4; j++) {
            int col = n0 + tx*4 + j;
            float v = acc[i][j];
            if constexpr (EPI == 4) {
                int b_ = row / NPATCH, p = row % NPATCH;
                int orow = b_*NTOK + 1 + p;
                C[(size_t)orow*EMB + col] = v + bias[col] + aux[(size_t)(1+p)*EMB + col];
            } else {
                if constexpr (EPI == 1) v += bias[col]*bias_scale;
                if constexpr (EPI == 2) v = C[(size_t)row*ldc + col] + v + bias[col];
                if constexpr (EPI == 3) { v += bias[col]; v = 0.5f*v*(1.0f + erff(v*0.70710678118654752f)); }
                C[(size_t)row*ldc + col] = v;
            }
        }
    }
}

// ---------------------------------------------------------------- SAT per-sample rows
__global__ __launch_bounds__(256) void sat_rows_kernel(
    const float* __restrict__ eleva, const float* __restrict__ eleva_var,
    const float* __restrict__ wq, const float* __restrict__ bq,
    const float* __restrict__ wk, const float* __restrict__ bk,
    const float* __restrict__ wv, const float* __restrict__ bv,
    const int* __restrict__ idx, float* __restrict__ proj, float* __restrict__ sconst)
{
    int s = blockIdx.x;
    __shared__ float ev[2][EMB];
    __shared__ float pr[6][SAT_D];
    int t = threadIdx.x;
    for (int i = t; i < 2*EMB; i += 256) {
        if (i < EMB) ev[0][i] = eleva[(size_t)idx[s]*EMB + i];
        else         ev[1][i-EMB] = eleva_var[(size_t)idx[16+s]*EMB + (i-EMB)];
    }
    __syncthreads();
    for (int j = 0; j < 6; j++) {
        const float* vec = ev[(j >= 3) ? 1 : 0];
        const float* Wm = (j%3 == 0) ? wq : ((j%3 == 1) ? wk : wv);
        const float* bm = (j%3 == 0) ? bq : ((j%3 == 1) ? bk : bv);
        float accv = bm[t];
        for (int k = 0; k < EMB; k++) accv += vec[k]*Wm[(size_t)k*SAT_D + t];
        pr[j][t] = accv;
        proj[((size_t)s*6 + j)*SAT_D + t] = accv;
    }
    __syncthreads();
    if (t < 32) {
        int h = t >> 2, c = t & 3;
        const float* qv = pr[(c < 2) ? 0 : 3];
        const float* kv = pr[((c & 1) == 0) ? 1 : 4];
        float d = 0.f;
        for (int x = 0; x < SAT_DK; x++) d += qv[h*32+x]*kv[h*32+x];
        sconst[((size_t)s*8 + h)*4 + c] = d * 0.17677669529663687f;
    }
}

// ---------------------------------------------------------------- SAT main (per token)
__global__ __launch_bounds__(256) void sat_attn_kernel(
    const float* __restrict__ qkv0, const float* __restrict__ proj,
    const float* __restrict__ sconst, float* __restrict__ osum)
{
    int b = blockIdx.x;
    int s = b & 15;
    __shared__ float pr[6][SAT_D];
    __shared__ float sc[8][4];
    for (int i = threadIdx.x; i < 6*SAT_D; i += 256) pr[i >> 8][i & 255] = proj[(size_t)s*6*SAT_D + i];
    if (threadIdx.x < 32) sc[threadIdx.x >> 2][threadIdx.x & 3] = sconst[(size_t)s*32 + threadIdx.x];
    __syncthreads();
    int t = threadIdx.x;
    if (t >= NTOK) return;
    size_t m = (size_t)b*NTOK + t;
    const float* q0 = qkv0 + m*768;
    const float* k0 = q0 + 256;
    const float* v0 = q0 + 512;
    const float inv = 0.17677669529663687f;
    for (int h = 0; h < SAT_H; h++) {
        int d0 = h*32;
        float S00=0,S01=0,S02=0,S10=0,S20=0;
        #pragma unroll 8
        for (int d = 0; d < 32; d++) {
            float qv = q0[d0+d], kv = k0[d0+d];
            S00 += qv*kv;
            S01 += qv*pr[1][d0+d];
            S02 += qv*pr[4][d0+d];
            S10 += pr[0][d0+d]*kv;
            S20 += pr[3][d0+d]*kv;
        }
        S00*=inv; S01*=inv; S02*=inv; S10*=inv; S20*=inv;
        float al=0.f, be=0.f, ga=0.f;
        {
            float mx = fmaxf(S00, fmaxf(S01, S02));
            float e0 = expf(S00-mx), e1 = expf(S01-mx), e2 = expf(S02-mx);
            float is = 1.0f/(e0+e1+e2); al += e0*is; be += e1*is; ga += e2*is;
        }
        {
            float a1 = sc[h][0], a2 = sc[h][1];
            float mx = fmaxf(S10, fmaxf(a1, a2));
            float e0 = expf(S10-mx), e1 = expf(a1-mx), e2 = expf(a2-mx);
            float is = 1.0f/(e0+e1+e2); al += e0*is; be += e1*is; ga += e2*is;
        }
        {
            float a1 = sc[h][2], a2 = sc[h][3];
            float mx = fmaxf(S20, fmaxf(a1, a2));
            float e0 = expf(S20-mx), e1 = expf(a1-mx), e2 = expf(a2-mx);
            float is = 1.0f/(e0+e1+e2); al += e0*is; be += e1*is; ga += e2*is;
        }
        #pragma unroll 8
        for (int d = 0; d < 32; d++)
            osum[m*SAT_D + d0 + d] = al*v0[d0+d] + be*pr[2][d0+d] + ga*pr[5][d0+d];
    }
}

// ---------------------------------------------------------------- ViT attention, flash-style
// grid: (qtile 0..12, head 0..2, crop 0..63); 16 queries/block, 4 waves.
// Phase 1: K in LDS (fp32, stride 76 -> 2-way banks = free), scores in regs (4 keys/lane),
//          wave-shuffle softmax, att -> LDS [q][200].
// Phase 2: V restaged over K's LDS, PV with 4 independent accumulators, lane = dim.
__global__ __launch_bounds__(256) void vit_flash_kernel(
    const float* __restrict__ qkv, float* __restrict__ hout)
{
    int qt = blockIdx.x, hd = blockIdx.y, b = blockIdx.z;
    __shared__ float KV[NTOK][76];
    __shared__ float Qs[16][68];
    __shared__ float attL[16][200];
    const float* base = qkv + (size_t)b*NTOK*576;
    int q0 = qt*16;
    int nq = NTOK - q0; if (nq > 16) nq = 16;
    int tid = threadIdx.x;
    // stage Q tile (zero-pad tail queries)
    for (int i = tid; i < 16*16; i += 256) {
        int q = i >> 4, dg = (i & 15) << 2;
        float4 v = make_float4(0.f,0.f,0.f,0.f);
        if (q < nq) v = *(const float4*)(base + (size_t)(q0+q)*576 + hd*64 + dg);
        *(float4*)&Qs[q][dg] = v;
    }
    // stage K
    for (int i = tid; i < NTOK*16; i += 256) {
        int k = i >> 4, dg = (i & 15) << 2;
        *(float4*)&KV[k][dg] = *(const float4*)(base + (size_t)k*576 + 192 + hd*64 + dg);
    }
    __syncthreads();
    int wave = tid >> 6, lane = tid & 63;
    const int kl3 = (lane < NTOK-192) ? lane + 192 : lane;   // safe row for tail keys
    const float scale = 0.125f;
    #pragma unroll
    for (int qi = 0; qi < 4; qi++) {
        int q = wave*4 + qi;
        float s0=0.f, s1=0.f, s2=0.f, s3=0.f;
        #pragma unroll
        for (int dg = 0; dg < 64; dg += 4) {
            float4 qv = *(const float4*)&Qs[q][dg];
            float4 k0 = *(const float4*)&KV[lane][dg];
            float4 k1 = *(const float4*)&KV[lane+64][dg];
            float4 k2 = *(const float4*)&KV[lane+128][dg];
            float4 k3 = *(const float4*)&KV[kl3][dg];
            s0 += qv.x*k0.x + qv.y*k0.y + qv.z*k0.z + qv.w*k0.w;
            s1 += qv.x*k1.x + qv.y*k1.y + qv.z*k1.z + qv.w*k1.w;
            s2 += qv.x*k2.x + qv.y*k2.y + qv.z*k2.z + qv.w*k2.w;
            s3 += qv.x*k3.x + qv.y*k3.y + qv.z*k3.z + qv.w*k3.w;
        }
        s0 *= scale; s1 *= scale; s2 *= scale;
        s3 = (lane < NTOK-192) ? s3*scale : -1e30f;
        float mx = fmaxf(fmaxf(s0,s1), fmaxf(s2,s3));
        for (int o = 32; o > 0; o >>= 1) mx = fmaxf(mx, __shfl_xor(mx, o));
        float e0 = expf(s0-mx), e1 = expf(s1-mx), e2 = expf(s2-mx);
        float e3 = (lane < NTOK-192) ? expf(s3-mx) : 0.f;
        float sm = e0+e1+e2+e3;
        for (int o = 32; o > 0; o >>= 1) sm += __shfl_xor(sm, o);
        float isv = 1.f/sm;
        attL[q][lane]       = e0*isv;
        attL[q][lane+64]    = e1*isv;
        attL[q][lane+128]   = e2*isv;
        if (lane < NTOK-192) attL[q][lane+192] = e3*isv;
    }
    __syncthreads();
    // restage V over K's LDS
    for (int i = tid; i < NTOK*16; i += 256) {
        int k = i >> 4, dg = (i & 15) << 2;
        *(float4*)&KV[k][dg] = *(const float4*)(base + (size_t)k*576 + 384 + hd*64 + dg);
    }
    __syncthreads();
    int qb = wave*4;
    float o0=0.f, o1=0.f, o2=0.f, o3=0.f;
    for (int k = 0; k < 196; k += 4) {
        float4 a0 = *(const float4*)&attL[qb+0][k];
        float4 a1 = *(const float4*)&attL[qb+1][k];
        float4 a2 = *(const float4*)&attL[qb+2][k];
        float4 a3 = *(const float4*)&attL[qb+3][k];
        float v0 = KV[k][lane], v1 = KV[k+1][lane], v2 = KV[k+2][lane], v3 = KV[k+3][lane];
        o0 += a0.x*v0 + a0.y*v1 + a0.z*v2 + a0.w*v3;
        o1 += a1.x*v0 + a1.y*v1 + a1.z*v2 + a1.w*v3;
        o2 += a2.x*v0 + a2.y*v1 + a2.z*v2 + a2.w*v3;
        o3 += a3.x*v0 + a3.y*v1 + a3.z*v2 + a3.w*v3;
    }
    {
        float v0 = KV[196][lane];
        o0 += attL[qb+0][196]*v0;
        o1 += attL[qb+1][196]*v0;
        o2 += attL[qb+2][196]*v0;
        o3 += attL[qb+3][196]*v0;
    }
    float* op = hout + ((size_t)b*NTOK + q0)*EMB + hd*64 + lane;
    if (qb+0 < nq) op[(size_t)(qb+0)*EMB] = o0;
    if (qb+1 < nq) op[(size_t)(qb+1)*EMB] = o1;
    if (qb+2 < nq) op[(size_t)(qb+2)*EMB] = o2;
    if (qb+3 < nq) op[(size_t)(qb+3)*EMB] = o3;
}

// ---------------------------------------------------------------- LayerNorm, 4 rows/block
__global__ __launch_bounds__(256) void ln_kernel(const float* __restrict__ in,
    const float* __restrict__ w, const float* __restrict__ b_, float* __restrict__ out, int nrows)
{
    int r = blockIdx.x*4 + (threadIdx.x >> 6);
    int lane = threadIdx.x & 63;
    if (r >= nrows) return;
    const float* x = in + (size_t)r*EMB;
    float x0 = x[lane], x1 = x[lane+64], x2 = x[lane+128];
    float s = x0+x1+x2;
    for (int o = 32; o > 0; o >>= 1) s += __shfl_xor(s, o);
    float mu = s * (1.0f/EMB);
    float d0 = x0-mu, d1 = x1-mu, d2 = x2-mu;
    float ss = d0*d0 + d1*d1 + d2*d2;
    for (int o = 32; o > 0; o >>= 1) ss += __shfl_xor(ss, o);
    float rs = rsqrtf(ss*(1.0f/EMB) + 1e-5f);
    float* y = out + (size_t)r*EMB;
    y[lane]     = d0*rs*w[lane]     + b_[lane];
    y[lane+64]  = d1*rs*w[lane+64]  + b_[lane+64];
    y[lane+128] = d2*rs*w[lane+128] + b_[lane+128];
}

// ---------------------------------------------------------------- final LN on t=0 rows only
__global__ __launch_bounds__(64) void final_ln_kernel(const float* __restrict__ tok,
    const float* __restrict__ w, const float* __restrict__ b_, float* __restrict__ out)
{
    int b = blockIdx.x, lane = threadIdx.x;
    const float* x = tok + (size_t)b*NTOK*EMB;
    float x0 = x[lane], x1 = x[lane+64], x2 = x[lane+128];
    float s = x0+x1+x2;
    for (int o = 32; o > 0; o >>= 1) s += __shfl_xor(s, o);
    float mu = s * (1.0f/EMB);
    float d0 = x0-mu, d1 = x1-mu, d2 = x2-mu;
    float ss = d0*d0 + d1*d1 + d2*d2;
    for (int o = 32; o > 0; o >>= 1) ss += __shfl_xor(ss, o);
    float rs = rsqrtf(ss*(1.0f/EMB) + 1e-5f);
    out[(size_t)b*EMB + lane]     = d0*rs*w[lane]     + b_[lane];
    out[(size_t)b*EMB + lane+64]  = d1*rs*w[lane+64]  + b_[lane+64];
    out[(size_t)b*EMB + lane+128] = d2*rs*w[lane+128] + b_[lane+128];
}

// ---------------------------------------------------------------- launch
extern "C" void kernel_launch(void* const* d_in, const int* in_sizes, int n_in,
                              void* d_out, int out_size, void* d_ws, size_t ws_size,
                              hipStream_t stream)
{
    const float* x          = (const float*)d_in[0];
    const float* xg         = (const float*)d_in[1];
    const float* per_li     = (const float*)d_in[2];
    const float* per_li_var = (const float*)d_in[3];
    const float* patch_w    = (const float*)d_in[4];
    const float* patch_b    = (const float*)d_in[5];
    const float* cls_token  = (const float*)d_in[6];
    const float* pos_embed  = (const float*)d_in[7];
    const float* eleva      = (const float*)d_in[8];
    const float* eleva_var  = (const float*)d_in[9];
    const float* sat_wq     = (const float*)d_in[10];
    const float* sat_bq     = (const float*)d_in[11];
    const float* sat_wk     = (const float*)d_in[12];
    const float* sat_bk     = (const float*)d_in[13];
    const float* sat_wv     = (const float*)d_in[14];
    const float* sat_bv     = (const float*)d_in[15];
    const float* sat_wo     = (const float*)d_in[16];
    const float* sat_bo     = (const float*)d_in[17];
    const float* ln1_w      = (const float*)d_in[18];
    const float* ln1_b      = (const float*)d_in[19];
    const float* qkv_w      = (const float*)d_in[20];
    const float* proj_w     = (const float*)d_in[21];
    const float* proj_b     = (const float*)d_in[22];
    const float* ln2_w      = (const float*)d_in[23];
    const float* ln2_b      = (const float*)d_in[24];
    const float* fc1_w      = (const float*)d_in[25];
    const float* fc1_b      = (const float*)d_in[26];
    const float* fc2_w      = (const float*)d_in[27];
    const float* fc2_b      = (const float*)d_in[28];
    const float* lnf_w      = (const float*)d_in[29];
    const float* lnf_b      = (const float*)d_in[30];
    float* out = (float*)d_out;

    float* ws    = (float*)d_ws;
    float* tok   = ws;                                   // 12608*192
    float* hbuf  = tok  + (size_t)M_TOK*EMB;             // 12608*192
    float* qkvb  = hbuf + (size_t)M_TOK*EMB;             // 12608*768 (also im2col / mlp-hidden)
    float* osum  = qkvb + (size_t)M_TOK*768;             // 12608*256
    float* projb = osum + (size_t)M_TOK*SAT_D;           // 16*6*256
    float* sconst= projb + 16*6*SAT_D;                   // 16*32
    int*   idxb  = (int*)(sconst + 16*32);               // 32 ints

    // elevation stats + bucketing
    stats_kernel<<<16, 256, 0, stream>>>(xg, per_li, per_li_var, idxb);
    // patch embed: im2col -> GEMM with pos-embed scatter epilogue
    im2col_kernel<<<(M_PATCH*768 + 255)/256, 256, 0, stream>>>(x, qkvb);
    gemm_kernel<true,4><<<dim3(EMB/64, M_PATCH/64), 256, 0, stream>>>(
        qkvb, patch_w, patch_b, pos_embed, tok, M_PATCH, EMB, 768, EMB, 1.0f);
    cls_kernel<<<(NB*EMB + 255)/256, 256, 0, stream>>>(cls_token, pos_embed, tok);
    // SAT: per-sample rows, token projections, tiny attention, output proj (bias*3, replaces tok)
    sat_rows_kernel<<<16, 256, 0, stream>>>(eleva, eleva_var, sat_wq, sat_bq, sat_wk, sat_bk,
                                            sat_wv, sat_bv, idxb, projb, sconst);
    gemm_kernel<false,1><<<dim3(SAT_D/64, M_TOK/64), 256, 0, stream>>>(
        tok, sat_wq, sat_bq, nullptr, qkvb + 0,   M_TOK, SAT_D, EMB, 768, 1.0f);
    gemm_kernel<false,1><<<dim3(SAT_D/64, M_TOK/64), 256, 0, stream>>>(
        tok, sat_wk, sat_bk, nullptr, qkvb + 256, M_TOK, SAT_D, EMB, 768, 1.0f);
    gemm_kernel<false,1><<<dim3(SAT_D/64, M_TOK/64), 256, 0, stream>>>(
        tok, sat_wv, sat_bv, nullptr, qkvb + 512, M_TOK, SAT_D, EMB, 768, 1.0f);
    sat_attn_kernel<<<NB, 256, 0, stream>>>(qkvb, projb, sconst, osum);
    gemm_kernel<false,1><<<dim3(EMB/64, M_TOK/64), 256, 0, stream>>>(
        osum, sat_wo, sat_bo, nullptr, tok, M_TOK, EMB, SAT_D, EMB, 3.0f);
    // ViT blocks
    for (int i = 0; i < DEPTH; i++) {
        ln_kernel<<<M_TOK/4, 256, 0, stream>>>(tok, ln1_w + i*EMB, ln1_b + i*EMB, hbuf, M_TOK);
        gemm_kernel<false,0><<<dim3(576/64, M_TOK/64), 256, 0, stream>>>(
            hbuf, qkv_w + (size_t)i*EMB*576, nullptr, nullptr, qkvb, M_TOK, 576, EMB, 576, 1.0f);
        vit_flash_kernel<<<dim3(13, NHEADS, NB), 256, 0, stream>>>(qkvb, hbuf);
        gemm_kernel<false,2><<<dim3(EMB/64, M_TOK/64), 256, 0, stream>>>(
            hbuf, proj_w + (size_t)i*EMB*EMB, proj_b + i*EMB, nullptr, tok, M_TOK, EMB, EMB, EMB, 1.0f);
        ln_kernel<<<M_TOK/4, 256, 0, stream>>>(tok, ln2_w + i*EMB, ln2_b + i*EMB, hbuf, M_TOK);
        gemm_kernel<false,3><<<dim3(MLPD/64, M_TOK/64), 256, 0, stream>>>(
            hbuf, fc1_w + (size_t)i*EMB*MLPD, fc1_b + i*MLPD, nullptr, qkvb, M_TOK, MLPD, EMB, MLPD, 1.0f);
        gemm_kernel<false,2><<<dim3(EMB/64, M_TOK/64), 256, 0, stream>>>(
            qkvb, fc2_w + (size_t)i*MLPD*EMB, fc2_b + i*EMB, nullptr, tok, M_TOK, EMB, MLPD, EMB, 1.0f);
    }
    final_ln_kernel<<<NB, 64, 0, stream>>>(tok, lnf_w, lnf_b, out);
}

// Round 4
// 2336.166 us; speedup vs baseline: 2.7912x; 1.8432x over previous
//
#include <hip/hip_runtime.h>
#include <hip/hip_bf16.h>
#include <math.h>

#define NB 64
#define NBT 16
#define IMG 224
#define CIN 3
#define EMB 192
#define NHEADS 3
#define DEPTH 12
#define MLPD (4*EMB)
#define NPATCH 196
#define NTOK 197
#define M_TOK (NB*NTOK)      // 12608
#define M_PATCH (NB*NPATCH)  // 12544
#define SAT_H 8
#define SAT_DK 32
#define SAT_D 256

typedef __attribute__((ext_vector_type(8))) short bf16x8;
typedef __attribute__((ext_vector_type(4))) float f32x4;
typedef __hip_bfloat16 bf16;

__device__ __forceinline__ float bf2f(ushort u) { return __uint_as_float(((unsigned)u) << 16); }

// ---------------------------------------------------------------- stats
__global__ __launch_bounds__(256) void stats_kernel(const float* __restrict__ xg,
    const float* __restrict__ per_li, const float* __restrict__ per_li_var,
    int* __restrict__ idx_out)
{
    int s = blockIdx.x;
    const float* row = xg + (size_t)s * (IMG*IMG);
    double lsum = 0.0, lsq = 0.0;
    for (int i = threadIdx.x; i < IMG*IMG; i += 256) {
        double v = (double)row[i]; lsum += v; lsq += v*v;
    }
    __shared__ double ssum[256], ssq[256];
    ssum[threadIdx.x] = lsum; ssq[threadIdx.x] = lsq;
    __syncthreads();
    for (int st = 128; st > 0; st >>= 1) {
        if (threadIdx.x < st) { ssum[threadIdx.x] += ssum[threadIdx.x+st]; ssq[threadIdx.x] += ssq[threadIdx.x+st]; }
        __syncthreads();
    }
    if (threadIdx.x == 0) {
        double n = (double)(IMG*IMG);
        double mean = ssum[0] / n;
        double var  = (ssq[0] - n*mean*mean) / (n - 1.0);
        int i1 = 0, i2 = 0;
        for (int j = 0; j < 15; j++) {
            if ((double)per_li[j] < mean) i1++;
            if ((double)per_li_var[j] < var) i2++;
        }
        idx_out[s] = i1; idx_out[16 + s] = i2;
    }
}

// ---------------------------------------------------------------- weight prep
// in [L][K][N] fp32 -> out [L][N][K] bf16
__global__ __launch_bounds__(256) void transpose_cast_kernel(const float* __restrict__ in,
    bf16* __restrict__ out, int K, int N)
{
    in  += (size_t)blockIdx.z*K*N;
    out += (size_t)blockIdx.z*N*K;
    __shared__ float t[32][33];
    int k0 = blockIdx.y*32, n0 = blockIdx.x*32;
    int tx = threadIdx.x & 31, ty = threadIdx.x >> 5;
    #pragma unroll
    for (int i = 0; i < 4; i++) {
        int k = ty + i*8;
        t[k][tx] = in[(size_t)(k0+k)*N + n0 + tx];
    }
    __syncthreads();
    #pragma unroll
    for (int i = 0; i < 4; i++) {
        int n = ty + i*8;
        out[(size_t)(n0+n)*K + k0 + tx] = __float2bfloat16(t[tx][n]);
    }
}

__global__ __launch_bounds__(256) void cast_kernel(const float* __restrict__ in, bf16* __restrict__ out, int n)
{
    int i = blockIdx.x*256 + threadIdx.x;
    if (i < n) out[i] = __float2bfloat16(in[i]);
}

// ---------------------------------------------------------------- im2col (bf16 out)
__global__ __launch_bounds__(256) void im2col_kernel(const float* __restrict__ x, bf16* __restrict__ out)
{
    int e = blockIdx.x*256 + threadIdx.x;
    if (e >= M_PATCH*768) return;
    int row = e / 768, col = e % 768;
    int b = row / NPATCH, p = row % NPATCH;
    int py = p / 14, px = p % 14;
    int c = col >> 8, r8 = col & 255;
    int i = r8 >> 4, j = r8 & 15;
    out[e] = __float2bfloat16(x[(((size_t)b*CIN + c)*IMG + py*16 + i)*IMG + px*16 + j]);
}

// ---------------------------------------------------------------- cls row (bf16)
__global__ void cls_kernel(const float* __restrict__ cls, const float* __restrict__ pos, bf16* __restrict__ tokb)
{
    int i = blockIdx.x*256 + threadIdx.x;
    if (i >= NB*EMB) return;
    int b = i / EMB, e = i % EMB;
    tokb[(size_t)(b*NTOK)*EMB + e] = __float2bfloat16(cls[e] + pos[e]);
}

// ---------------------------------------------------------------- MFMA bf16 GEMM
// C = A[M][K]bf16 @ Wt[N][K]bf16 (+epilogue). 64x64 tile, BK=64, 4 waves (2x2), 2x2 frags/wave.
// EPI: 0 none, 1 +bias*scale, 2 fp32 C += acc+bias (residual), 3 gelu(acc+bias), 4 patch scatter
template<int EPI, bool OBF>
__global__ __launch_bounds__(256) void mfma_gemm(
    const bf16* __restrict__ A, const bf16* __restrict__ Wt,
    const float* __restrict__ bias, const float* __restrict__ aux,
    void* __restrict__ Cv, int M, int N, int K, int ldc, float bias_scale)
{
    __shared__ bf16 As[64][72];
    __shared__ bf16 Bs[64][72];
    int tid = threadIdx.x;
    int wave = tid >> 6, lane = tid & 63;
    int wm = wave >> 1, wn = wave & 1;
    int m0 = blockIdx.y*64, n0 = blockIdx.x*64;
    f32x4 acc[2][2] = {};
    int sr = tid >> 3, sc = (tid & 7) * 8;      // staging: row 0..31, col-8 group

    for (int k0 = 0; k0 < K; k0 += 64) {
        #pragma unroll
        for (int it = 0; it < 2; it++) {
            int r = sr + it*32;
            *(uint4*)&As[r][sc] = *(const uint4*)(A  + (size_t)(m0 + r)*K + k0 + sc);
            *(uint4*)&Bs[r][sc] = *(const uint4*)(Wt + (size_t)(n0 + r)*K + k0 + sc);
        }
        __syncthreads();
        #pragma unroll
        for (int ks = 0; ks < 2; ks++) {
            int ko = ks*32 + (lane >> 4)*8;
            bf16x8 af[2], bfr[2];
            #pragma unroll
            for (int mi = 0; mi < 2; mi++) af[mi]  = *(const bf16x8*)&As[wm*32 + mi*16 + (lane & 15)][ko];
            #pragma unroll
            for (int ni = 0; ni < 2; ni++) bfr[ni] = *(const bf16x8*)&Bs[wn*32 + ni*16 + (lane & 15)][ko];
            #pragma unroll
            for (int mi = 0; mi < 2; mi++)
                #pragma unroll
                for (int ni = 0; ni < 2; ni++)
                    acc[mi][ni] = __builtin_amdgcn_mfma_f32_16x16x32_bf16(af[mi], bfr[ni], acc[mi][ni], 0, 0, 0);
        }
        __syncthreads();
    }
    #pragma unroll
    for (int mi = 0; mi < 2; mi++) {
        #pragma unroll
        for (int ni = 0; ni < 2; ni++) {
            int rbase = m0 + wm*32 + mi*16 + (lane >> 4)*4;
            int col   = n0 + wn*32 + ni*16 + (lane & 15);
            #pragma unroll
            for (int r = 0; r < 4; r++) {
                int row = rbase + r;
                float v = acc[mi][ni][r];
                if constexpr (EPI == 4) {
                    int b_ = row / NPATCH, p = row % NPATCH;
                    ((bf16*)Cv)[(size_t)(b_*NTOK + 1 + p)*EMB + col] =
                        __float2bfloat16(v + bias[col] + aux[(size_t)(1+p)*EMB + col]);
                } else {
                    if constexpr (EPI == 1) v += bias[col]*bias_scale;
                    if constexpr (EPI == 2) v = ((float*)Cv)[(size_t)row*ldc + col] + v + bias[col];
                    if constexpr (EPI == 3) { v += bias[col]; v = 0.5f*v*(1.0f + erff(v*0.70710678118654752f)); }
                    if constexpr (OBF) ((bf16*)Cv)[(size_t)row*ldc + col] = __float2bfloat16(v);
                    else               ((float*)Cv)[(size_t)row*ldc + col] = v;
                }
            }
        }
    }
}

// ---------------------------------------------------------------- SAT per-sample rows (fp32, tiny)
__global__ __launch_bounds__(256) void sat_rows_kernel(
    const float* __restrict__ eleva, const float* __restrict__ eleva_var,
    const float* __restrict__ wq, const float* __restrict__ bq,
    const float* __restrict__ wk, const float* __restrict__ bk,
    const float* __restrict__ wv, const float* __restrict__ bv,
    const int* __restrict__ idx, float* __restrict__ proj, float* __restrict__ sconst)
{
    int s = blockIdx.x;
    __shared__ float ev[2][EMB];
    __shared__ float pr[6][SAT_D];
    int t = threadIdx.x;
    for (int i = t; i < 2*EMB; i += 256) {
        if (i < EMB) ev[0][i] = eleva[(size_t)idx[s]*EMB + i];
        else         ev[1][i-EMB] = eleva_var[(size_t)idx[16+s]*EMB + (i-EMB)];
    }
    __syncthreads();
    for (int j = 0; j < 6; j++) {
        const float* vec = ev[(j >= 3) ? 1 : 0];
        const float* Wm = (j%3 == 0) ? wq : ((j%3 == 1) ? wk : wv);
        const float* bm = (j%3 == 0) ? bq : ((j%3 == 1) ? bk : bv);
        float accv = bm[t];
        for (int k = 0; k < EMB; k++) accv += vec[k]*Wm[(size_t)k*SAT_D + t];
        pr[j][t] = accv;
        proj[((size_t)s*6 + j)*SAT_D + t] = accv;
    }
    __syncthreads();
    if (t < 32) {
        int h = t >> 2, c = t & 3;
        const float* qv = pr[(c < 2) ? 0 : 3];
        const float* kv = pr[((c & 1) == 0) ? 1 : 4];
        float d = 0.f;
        for (int x = 0; x < SAT_DK; x++) d += qv[h*32+x]*kv[h*32+x];
        sconst[((size_t)s*8 + h)*4 + c] = d * 0.17677669529663687f;
    }
}

// ---------------------------------------------------------------- SAT main (per token, bf16 io)
__global__ __launch_bounds__(256) void sat_attn_kernel(
    const bf16* __restrict__ qkv0, const float* __restrict__ proj,
    const float* __restrict__ sconst, bf16* __restrict__ osum)
{
    int b = blockIdx.x;
    int s = b & 15;
    __shared__ float pr[6][SAT_D];
    __shared__ float sc[8][4];
    for (int i = threadIdx.x; i < 6*SAT_D; i += 256) pr[i >> 8][i & 255] = proj[(size_t)s*6*SAT_D + i];
    if (threadIdx.x < 32) sc[threadIdx.x >> 2][threadIdx.x & 3] = sconst[(size_t)s*32 + threadIdx.x];
    __syncthreads();
    int t = threadIdx.x;
    if (t >= NTOK) return;
    size_t m = (size_t)b*NTOK + t;
    const ushort* q0 = (const ushort*)(qkv0 + m*768);
    const ushort* k0 = q0 + 256;
    const ushort* v0 = q0 + 512;
    const float inv = 0.17677669529663687f;
    for (int h = 0; h < SAT_H; h++) {
        int d0 = h*32;
        float S00=0,S01=0,S02=0,S10=0,S20=0;
        #pragma unroll 8
        for (int d = 0; d < 32; d++) {
            float qv = bf2f(q0[d0+d]), kv = bf2f(k0[d0+d]);
            S00 += qv*kv;
            S01 += qv*pr[1][d0+d];
            S02 += qv*pr[4][d0+d];
            S10 += pr[0][d0+d]*kv;
            S20 += pr[3][d0+d]*kv;
        }
        S00*=inv; S01*=inv; S02*=inv; S10*=inv; S20*=inv;
        float al=0.f, be=0.f, ga=0.f;
        {
            float mx = fmaxf(S00, fmaxf(S01, S02));
            float e0 = expf(S00-mx), e1 = expf(S01-mx), e2 = expf(S02-mx);
            float is = 1.0f/(e0+e1+e2); al += e0*is; be += e1*is; ga += e2*is;
        }
        {
            float a1 = sc[h][0], a2 = sc[h][1];
            float mx = fmaxf(S10, fmaxf(a1, a2));
            float e0 = expf(S10-mx), e1 = expf(a1-mx), e2 = expf(a2-mx);
            float is = 1.0f/(e0+e1+e2); al += e0*is; be += e1*is; ga += e2*is;
        }
        {
            float a1 = sc[h][2], a2 = sc[h][3];
            float mx = fmaxf(S20, fmaxf(a1, a2));
            float e0 = expf(S20-mx), e1 = expf(a1-mx), e2 = expf(a2-mx);
            float is = 1.0f/(e0+e1+e2); al += e0*is; be += e1*is; ga += e2*is;
        }
        #pragma unroll 8
        for (int d = 0; d < 32; d++)
            osum[m*SAT_D + d0 + d] = __float2bfloat16(al*bf2f(v0[d0+d]) + be*pr[2][d0+d] + ga*pr[5][d0+d]);
    }
}

// ---------------------------------------------------------------- ViT attention (bf16 in/out, XCD-swizzled)
__global__ __launch_bounds__(256) void vit_flash_kernel(
    const bf16* __restrict__ qkv, bf16* __restrict__ hout)
{
    // bijective XCD swizzle: 2496 blocks, 8 XCDs, 312 per XCD; each XCD owns 8 consecutive crops
    int wg = blockIdx.x;
    int swz = (wg & 7)*312 + (wg >> 3);
    int b = swz / 39, wc = swz % 39;
    int qt = wc / 3, hd = wc % 3;

    __shared__ float KV[NTOK][76];
    __shared__ float Qs[16][68];
    __shared__ float attL[16][200];
    const bf16* base = qkv + (size_t)b*NTOK*576;
    int q0 = qt*16;
    int nq = NTOK - q0; if (nq > 16) nq = 16;
    int tid = threadIdx.x;
    // stage Q tile (zero-pad tail queries)
    for (int i = tid; i < 16*8; i += 256) {
        int q = i >> 3, dg = (i & 7) << 3;
        float f[8] = {0,0,0,0,0,0,0,0};
        if (q < nq) {
            uint4 raw = *(const uint4*)(base + (size_t)(q0+q)*576 + hd*64 + dg);
            const ushort* u = (const ushort*)&raw;
            #pragma unroll
            for (int j = 0; j < 8; j++) f[j] = bf2f(u[j]);
        }
        #pragma unroll
        for (int j = 0; j < 8; j++) Qs[q][dg+j] = f[j];
    }
    // stage K
    for (int i = tid; i < NTOK*8; i += 256) {
        int k = i >> 3, dg = (i & 7) << 3;
        uint4 raw = *(const uint4*)(base + (size_t)k*576 + 192 + hd*64 + dg);
        const ushort* u = (const ushort*)&raw;
        #pragma unroll
        for (int j = 0; j < 8; j++) KV[k][dg+j] = bf2f(u[j]);
    }
    __syncthreads();
    int wave = tid >> 6, lane = tid & 63;
    const int kl3 = (lane < NTOK-192) ? lane + 192 : lane;
    const float scale = 0.125f;
    #pragma unroll
    for (int qi = 0; qi < 4; qi++) {
        int q = wave*4 + qi;
        float s0=0.f, s1=0.f, s2=0.f, s3=0.f;
        #pragma unroll
        for (int dg = 0; dg < 64; dg += 4) {
            float4 qv = *(const float4*)&Qs[q][dg];
            float4 k0 = *(const float4*)&KV[lane][dg];
            float4 k1 = *(const float4*)&KV[lane+64][dg];
            float4 k2 = *(const float4*)&KV[lane+128][dg];
            float4 k3 = *(const float4*)&KV[kl3][dg];
            s0 += qv.x*k0.x + qv.y*k0.y + qv.z*k0.z + qv.w*k0.w;
            s1 += qv.x*k1.x + qv.y*k1.y + qv.z*k1.z + qv.w*k1.w;
            s2 += qv.x*k2.x + qv.y*k2.y + qv.z*k2.z + qv.w*k2.w;
            s3 += qv.x*k3.x + qv.y*k3.y + qv.z*k3.z + qv.w*k3.w;
        }
        s0 *= scale; s1 *= scale; s2 *= scale;
        s3 = (lane < NTOK-192) ? s3*scale : -1e30f;
        float mx = fmaxf(fmaxf(s0,s1), fmaxf(s2,s3));
        for (int o = 32; o > 0; o >>= 1) mx = fmaxf(mx, __shfl_xor(mx, o));
        float e0 = expf(s0-mx), e1 = expf(s1-mx), e2 = expf(s2-mx);
        float e3 = (lane < NTOK-192) ? expf(s3-mx) : 0.f;
        float sm = e0+e1+e2+e3;
        for (int o = 32; o > 0; o >>= 1) sm += __shfl_xor(sm, o);
        float isv = 1.f/sm;
        attL[q][lane]       = e0*isv;
        attL[q][lane+64]    = e1*isv;
        attL[q][lane+128]   = e2*isv;
        if (lane < NTOK-192) attL[q][lane+192] = e3*isv;
    }
    __syncthreads();
    // restage V over K's LDS
    for (int i = tid; i < NTOK*8; i += 256) {
        int k = i >> 3, dg = (i & 7) << 3;
        uint4 raw = *(const uint4*)(base + (size_t)k*576 + 384 + hd*64 + dg);
        const ushort* u = (const ushort*)&raw;
        #pragma unroll
        for (int j = 0; j < 8; j++) KV[k][dg+j] = bf2f(u[j]);
    }
    __syncthreads();
    int qb = wave*4;
    float o0=0.f, o1=0.f, o2=0.f, o3=0.f;
    for (int k = 0; k < 196; k += 4) {
        float4 a0 = *(const float4*)&attL[qb+0][k];
        float4 a1 = *(const float4*)&attL[qb+1][k];
        float4 a2 = *(const float4*)&attL[qb+2][k];
        float4 a3 = *(const float4*)&attL[qb+3][k];
        float v0 = KV[k][lane], v1 = KV[k+1][lane], v2 = KV[k+2][lane], v3 = KV[k+3][lane];
        o0 += a0.x*v0 + a0.y*v1 + a0.z*v2 + a0.w*v3;
        o1 += a1.x*v0 + a1.y*v1 + a1.z*v2 + a1.w*v3;
        o2 += a2.x*v0 + a2.y*v1 + a2.z*v2 + a2.w*v3;
        o3 += a3.x*v0 + a3.y*v1 + a3.z*v2 + a3.w*v3;
    }
    {
        float v0 = KV[196][lane];
        o0 += attL[qb+0][196]*v0;
        o1 += attL[qb+1][196]*v0;
        o2 += attL[qb+2][196]*v0;
        o3 += attL[qb+3][196]*v0;
    }
    bf16* op = hout + ((size_t)b*NTOK + q0)*EMB + hd*64 + lane;
    if (qb+0 < nq) op[(size_t)(qb+0)*EMB] = __float2bfloat16(o0);
    if (qb+1 < nq) op[(size_t)(qb+1)*EMB] = __float2bfloat16(o1);
    if (qb+2 < nq) op[(size_t)(qb+2)*EMB] = __float2bfloat16(o2);
    if (qb+3 < nq) op[(size_t)(qb+3)*EMB] = __float2bfloat16(o3);
}

// ---------------------------------------------------------------- LayerNorm fp32 -> bf16, 4 rows/block
__global__ __launch_bounds__(256) void ln_kernel(const float* __restrict__ in,
    const float* __restrict__ w, const float* __restrict__ b_, bf16* __restrict__ out, int nrows)
{
    int r = blockIdx.x*4 + (threadIdx.x >> 6);
    int lane = threadIdx.x & 63;
    if (r >= nrows) return;
    const float* x = in + (size_t)r*EMB;
    float x0 = x[lane], x1 = x[lane+64], x2 = x[lane+128];
    float s = x0+x1+x2;
    for (int o = 32; o > 0; o >>= 1) s += __shfl_xor(s, o);
    float mu = s * (1.0f/EMB);
    float d0 = x0-mu, d1 = x1-mu, d2 = x2-mu;
    float ss = d0*d0 + d1*d1 + d2*d2;
    for (int o = 32; o > 0; o >>= 1) ss += __shfl_xor(ss, o);
    float rs = rsqrtf(ss*(1.0f/EMB) + 1e-5f);
    bf16* y = out + (size_t)r*EMB;
    y[lane]     = __float2bfloat16(d0*rs*w[lane]     + b_[lane]);
    y[lane+64]  = __float2bfloat16(d1*rs*w[lane+64]  + b_[lane+64]);
    y[lane+128] = __float2bfloat16(d2*rs*w[lane+128] + b_[lane+128]);
}

// ---------------------------------------------------------------- final LN on t=0 rows only
__global__ __launch_bounds__(64) void final_ln_kernel(const float* __restrict__ tok,
    const float* __restrict__ w, const float* __restrict__ b_, float* __restrict__ out)
{
    int b = blockIdx.x, lane = threadIdx.x;
    const float* x = tok + (size_t)b*NTOK*EMB;
    float x0 = x[lane], x1 = x[lane+64], x2 = x[lane+128];
    float s = x0+x1+x2;
    for (int o = 32; o > 0; o >>= 1) s += __shfl_xor(s, o);
    float mu = s * (1.0f/EMB);
    float d0 = x0-mu, d1 = x1-mu, d2 = x2-mu;
    float ss = d0*d0 + d1*d1 + d2*d2;
    for (int o = 32; o > 0; o >>= 1) ss += __shfl_xor(ss, o);
    float rs = rsqrtf(ss*(1.0f/EMB) + 1e-5f);
    out[(size_t)b*EMB + lane]     = d0*rs*w[lane]     + b_[lane];
    out[(size_t)b*EMB + lane+64]  = d1*rs*w[lane+64]  + b_[lane+64];
    out[(size_t)b*EMB + lane+128] = d2*rs*w[lane+128] + b_[lane+128];
}

// ---------------------------------------------------------------- launch
extern "C" void kernel_launch(void* const* d_in, const int* in_sizes, int n_in,
                              void* d_out, int out_size, void* d_ws, size_t ws_size,
                              hipStream_t stream)
{
    const float* x          = (const float*)d_in[0];
    const float* xg         = (const float*)d_in[1];
    const float* per_li     = (const float*)d_in[2];
    const float* per_li_var = (const float*)d_in[3];
    const float* patch_w    = (const float*)d_in[4];
    const float* patch_b    = (const float*)d_in[5];
    const float* cls_token  = (const float*)d_in[6];
    const float* pos_embed  = (const float*)d_in[7];
    const float* eleva      = (const float*)d_in[8];
    const float* eleva_var  = (const float*)d_in[9];
    const float* sat_wq     = (const float*)d_in[10];
    const float* sat_bq     = (const float*)d_in[11];
    const float* sat_wk     = (const float*)d_in[12];
    const float* sat_bk     = (const float*)d_in[13];
    const float* sat_wv     = (const float*)d_in[14];
    const float* sat_bv     = (const float*)d_in[15];
    const float* sat_wo     = (const float*)d_in[16];
    const float* sat_bo     = (const float*)d_in[17];
    const float* ln1_w      = (const float*)d_in[18];
    const float* ln1_b      = (const float*)d_in[19];
    const float* qkv_w      = (const float*)d_in[20];
    const float* proj_w     = (const float*)d_in[21];
    const float* proj_b     = (const float*)d_in[22];
    const float* ln2_w      = (const float*)d_in[23];
    const float* ln2_b      = (const float*)d_in[24];
    const float* fc1_w      = (const float*)d_in[25];
    const float* fc1_b      = (const float*)d_in[26];
    const float* fc2_w      = (const float*)d_in[27];
    const float* fc2_b      = (const float*)d_in[28];
    const float* lnf_w      = (const float*)d_in[29];
    const float* lnf_b      = (const float*)d_in[30];
    float* out = (float*)d_out;

    char* p = (char*)d_ws;
    float* tokf = (float*)p;                 p += (size_t)M_TOK*EMB*4;
    bf16* hb    = (bf16*)p;                  p += (size_t)M_TOK*EMB*2;
    bf16* tokb  = (bf16*)p;                  p += (size_t)M_TOK*EMB*2;
    bf16* qkvb  = (bf16*)p;                  p += (size_t)M_TOK*768*2;
    bf16* osum  = (bf16*)p;                  p += (size_t)M_TOK*SAT_D*2;
    bf16* qkv_wt  = (bf16*)p;                p += (size_t)DEPTH*576*EMB*2;
    bf16* proj_wt = (bf16*)p;                p += (size_t)DEPTH*EMB*EMB*2;
    bf16* fc1_wt  = (bf16*)p;                p += (size_t)DEPTH*MLPD*EMB*2;
    bf16* fc2_wt  = (bf16*)p;                p += (size_t)DEPTH*EMB*MLPD*2;
    bf16* patch_wb= (bf16*)p;                p += (size_t)EMB*768*2;
    bf16* sat_wqt = (bf16*)p;                p += (size_t)SAT_D*EMB*2;
    bf16* sat_wkt = (bf16*)p;                p += (size_t)SAT_D*EMB*2;
    bf16* sat_wvt = (bf16*)p;                p += (size_t)SAT_D*EMB*2;
    bf16* sat_wot = (bf16*)p;                p += (size_t)EMB*SAT_D*2;
    float* projb  = (float*)p;               p += 16*6*SAT_D*4;
    float* sconst = (float*)p;               p += 16*32*4;
    int*   idxb   = (int*)p;

    // ---- weight prep (bf16, [N][K] transposed) ----
    transpose_cast_kernel<<<dim3(576/32, EMB/32, DEPTH), 256, 0, stream>>>(qkv_w,  qkv_wt,  EMB, 576);
    transpose_cast_kernel<<<dim3(EMB/32, EMB/32, DEPTH), 256, 0, stream>>>(proj_w, proj_wt, EMB, EMB);
    transpose_cast_kernel<<<dim3(MLPD/32, EMB/32, DEPTH), 256, 0, stream>>>(fc1_w, fc1_wt,  EMB, MLPD);
    transpose_cast_kernel<<<dim3(EMB/32, MLPD/32, DEPTH), 256, 0, stream>>>(fc2_w, fc2_wt,  MLPD, EMB);
    transpose_cast_kernel<<<dim3(SAT_D/32, EMB/32, 1), 256, 0, stream>>>(sat_wq, sat_wqt, EMB, SAT_D);
    transpose_cast_kernel<<<dim3(SAT_D/32, EMB/32, 1), 256, 0, stream>>>(sat_wk, sat_wkt, EMB, SAT_D);
    transpose_cast_kernel<<<dim3(SAT_D/32, EMB/32, 1), 256, 0, stream>>>(sat_wv, sat_wvt, EMB, SAT_D);
    transpose_cast_kernel<<<dim3(EMB/32, SAT_D/32, 1), 256, 0, stream>>>(sat_wo, sat_wot, SAT_D, EMB);
    cast_kernel<<<(EMB*768 + 255)/256, 256, 0, stream>>>(patch_w, patch_wb, EMB*768);

    // ---- elevation stats ----
    stats_kernel<<<16, 256, 0, stream>>>(xg, per_li, per_li_var, idxb);
    // ---- patch embed ----
    im2col_kernel<<<(M_PATCH*768 + 255)/256, 256, 0, stream>>>(x, qkvb);
    mfma_gemm<4,true><<<dim3(EMB/64, M_PATCH/64), 256, 0, stream>>>(
        qkvb, patch_wb, patch_b, pos_embed, tokb, M_PATCH, EMB, 768, EMB, 1.0f);
    cls_kernel<<<(NB*EMB + 255)/256, 256, 0, stream>>>(cls_token, pos_embed, tokb);
    // ---- SAT ----
    sat_rows_kernel<<<16, 256, 0, stream>>>(eleva, eleva_var, sat_wq, sat_bq, sat_wk, sat_bk,
                                            sat_wv, sat_bv, idxb, projb, sconst);
    mfma_gemm<1,true><<<dim3(SAT_D/64, M_TOK/64), 256, 0, stream>>>(
        tokb, sat_wqt, sat_bq, nullptr, qkvb + 0,   M_TOK, SAT_D, EMB, 768, 1.0f);
    mfma_gemm<1,true><<<dim3(SAT_D/64, M_TOK/64), 256, 0, stream>>>(
        tokb, sat_wkt, sat_bk, nullptr, qkvb + 256, M_TOK, SAT_D, EMB, 768, 1.0f);
    mfma_gemm<1,true><<<dim3(SAT_D/64, M_TOK/64), 256, 0, stream>>>(
        tokb, sat_wvt, sat_bv, nullptr, qkvb + 512, M_TOK, SAT_D, EMB, 768, 1.0f);
    sat_attn_kernel<<<NB, 256, 0, stream>>>(qkvb, projb, sconst, osum);
    mfma_gemm<1,false><<<dim3(EMB/64, M_TOK/64), 256, 0, stream>>>(
        osum, sat_wot, sat_bo, nullptr, tokf, M_TOK, EMB, SAT_D, EMB, 3.0f);
    // ---- ViT blocks ----
    for (int i = 0; i < DEPTH; i++) {
        ln_kernel<<<M_TOK/4, 256, 0, stream>>>(tokf, ln1_w + i*EMB, ln1_b + i*EMB, hb, M_TOK);
        mfma_gemm<0,true><<<dim3(576/64, M_TOK/64), 256, 0, stream>>>(
            hb, qkv_wt + (size_t)i*576*EMB, nullptr, nullptr, qkvb, M_TOK, 576, EMB, 576, 1.0f);
        vit_flash_kernel<<<2496, 256, 0, stream>>>(qkvb, hb);
        mfma_gemm<2,false><<<dim3(EMB/64, M_TOK/64), 256, 0, stream>>>(
            hb, proj_wt + (size_t)i*EMB*EMB, proj_b + i*EMB, nullptr, tokf, M_TOK, EMB, EMB, EMB, 1.0f);
        ln_kernel<<<M_TOK/4, 256, 0, stream>>>(tokf, ln2_w + i*EMB, ln2_b + i*EMB, hb, M_TOK);
        mfma_gemm<3,true><<<dim3(MLPD/64, M_TOK/64), 256, 0, stream>>>(
            hb, fc1_wt + (size_t)i*MLPD*EMB, fc1_b + i*MLPD, nullptr, qkvb, M_TOK, MLPD, EMB, MLPD, 1.0f);
        mfma_gemm<2,false><<<dim3(EMB/64, M_TOK/64), 256, 0, stream>>>(
            qkvb, fc2_wt + (size_t)i*EMB*MLPD, fc2_b + i*EMB, nullptr, tokf, M_TOK, EMB, MLPD, EMB, 1.0f);
    }
    final_ln_kernel<<<NB, 64, 0, stream>>>(tokf, lnf_w, lnf_b, out);
}

// Round 6
// 1635.546 us; speedup vs baseline: 3.9869x; 1.4284x over previous
//
#include <hip/hip_runtime.h>
#include <hip/hip_bf16.h>
#include <math.h>

#define NB 64
#define NBT 16
#define IMG 224
#define CIN 3
#define EMB 192
#define NHEADS 3
#define DEPTH 12
#define MLPD (4*EMB)
#define NPATCH 196
#define NTOK 197
#define M_TOK (NB*NTOK)      // 12608
#define M_PATCH (NB*NPATCH)  // 12544
#define SAT_H 8
#define SAT_DK 32
#define SAT_D 256
#define KPV 232              // P/Vt key-stride (bank-balanced, 16B-aligned)

typedef __attribute__((ext_vector_type(8))) short bf16x8;
typedef __attribute__((ext_vector_type(4))) float f32x4;
typedef __hip_bfloat16 bf16;

__device__ __forceinline__ float bf2f(ushort u) { return __uint_as_float(((unsigned)u) << 16); }
__device__ __forceinline__ ushort f2bf(float f) {
    bf16 h = __float2bfloat16(f);
    return *reinterpret_cast<ushort*>(&h);
}

// ---------------------------------------------------------------- stats
__global__ __launch_bounds__(256) void stats_kernel(const float* __restrict__ xg,
    const float* __restrict__ per_li, const float* __restrict__ per_li_var,
    int* __restrict__ idx_out)
{
    int s = blockIdx.x;
    const float* row = xg + (size_t)s * (IMG*IMG);
    double lsum = 0.0, lsq = 0.0;
    for (int i = threadIdx.x; i < IMG*IMG; i += 256) {
        double v = (double)row[i]; lsum += v; lsq += v*v;
    }
    __shared__ double ssum[256], ssq[256];
    ssum[threadIdx.x] = lsum; ssq[threadIdx.x] = lsq;
    __syncthreads();
    for (int st = 128; st > 0; st >>= 1) {
        if (threadIdx.x < st) { ssum[threadIdx.x] += ssum[threadIdx.x+st]; ssq[threadIdx.x] += ssq[threadIdx.x+st]; }
        __syncthreads();
    }
    if (threadIdx.x == 0) {
        double n = (double)(IMG*IMG);
        double mean = ssum[0] / n;
        double var  = (ssq[0] - n*mean*mean) / (n - 1.0);
        int i1 = 0, i2 = 0;
        for (int j = 0; j < 15; j++) {
            if ((double)per_li[j] < mean) i1++;
            if ((double)per_li_var[j] < var) i2++;
        }
        idx_out[s] = i1; idx_out[16 + s] = i2;
    }
}

// ---------------------------------------------------------------- weight prep
// in [L][K][N] fp32 -> out [L][N][K] bf16
__global__ __launch_bounds__(256) void transpose_cast_kernel(const float* __restrict__ in,
    bf16* __restrict__ out, int K, int N)
{
    in  += (size_t)blockIdx.z*K*N;
    out += (size_t)blockIdx.z*N*K;
    __shared__ float t[32][33];
    int k0 = blockIdx.y*32, n0 = blockIdx.x*32;
    int tx = threadIdx.x & 31, ty = threadIdx.x >> 5;
    #pragma unroll
    for (int i = 0; i < 4; i++) {
        int k = ty + i*8;
        t[k][tx] = in[(size_t)(k0+k)*N + n0 + tx];
    }
    __syncthreads();
    #pragma unroll
    for (int i = 0; i < 4; i++) {
        int n = ty + i*8;
        out[(size_t)(n0+n)*K + k0 + tx] = __float2bfloat16(t[tx][n]);
    }
}

__global__ __launch_bounds__(256) void cast_kernel(const float* __restrict__ in, bf16* __restrict__ out, int n)
{
    int i = blockIdx.x*256 + threadIdx.x;
    if (i < n) out[i] = __float2bfloat16(in[i]);
}

// ---------------------------------------------------------------- im2col (bf16 out)
__global__ __launch_bounds__(256) void im2col_kernel(const float* __restrict__ x, bf16* __restrict__ out)
{
    int e = blockIdx.x*256 + threadIdx.x;
    if (e >= M_PATCH*768) return;
    int row = e / 768, col = e % 768;
    int b = row / NPATCH, p = row % NPATCH;
    int py = p / 14, px = p % 14;
    int c = col >> 8, r8 = col & 255;
    int i = r8 >> 4, j = r8 & 15;
    out[e] = __float2bfloat16(x[(((size_t)b*CIN + c)*IMG + py*16 + i)*IMG + px*16 + j]);
}

// ---------------------------------------------------------------- cls row (bf16)
__global__ void cls_kernel(const float* __restrict__ cls, const float* __restrict__ pos, bf16* __restrict__ tokb)
{
    int i = blockIdx.x*256 + threadIdx.x;
    if (i >= NB*EMB) return;
    int b = i / EMB, e = i % EMB;
    tokb[(size_t)(b*NTOK)*EMB + e] = __float2bfloat16(cls[e] + pos[e]);
}

// ---------------------------------------------------------------- MFMA bf16 GEMM
// C = A[M][K]bf16 @ Wt[N][K]bf16 (+epilogue). 64x64 tile, BK=64, 4 waves (2x2), 2x2 frags/wave.
// EPI: 0 none, 1 +bias*scale, 2 fp32 C += acc+bias, 3 gelu(acc+bias), 4 patch scatter,
//      5 V-transpose scatter into vT[(b*3+hd)*64+d][KPV] (row=d_global, col=tok_global; no bias)
template<int EPI, bool OBF>
__global__ __launch_bounds__(256) void mfma_gemm(
    const bf16* __restrict__ A, const bf16* __restrict__ Wt,
    const float* __restrict__ bias, const float* __restrict__ aux,
    void* __restrict__ Cv, int M, int N, int K, int ldc, float bias_scale)
{
    __shared__ bf16 As[64][72];
    __shared__ bf16 Bs[64][72];
    int tid = threadIdx.x;
    int wave = tid >> 6, lane = tid & 63;
    int wm = wave >> 1, wn = wave & 1;
    int m0 = blockIdx.y*64, n0 = blockIdx.x*64;
    f32x4 acc[2][2] = {};
    int sr = tid >> 3, sc = (tid & 7) * 8;

    for (int k0 = 0; k0 < K; k0 += 64) {
        #pragma unroll
        for (int it = 0; it < 2; it++) {
            int r = sr + it*32;
            *(uint4*)&As[r][sc] = *(const uint4*)(A  + (size_t)(m0 + r)*K + k0 + sc);
            *(uint4*)&Bs[r][sc] = *(const uint4*)(Wt + (size_t)(n0 + r)*K + k0 + sc);
        }
        __syncthreads();
        #pragma unroll
        for (int ks = 0; ks < 2; ks++) {
            int ko = ks*32 + (lane >> 4)*8;
            bf16x8 af[2], bfr[2];
            #pragma unroll
            for (int mi = 0; mi < 2; mi++) af[mi]  = *(const bf16x8*)&As[wm*32 + mi*16 + (lane & 15)][ko];
            #pragma unroll
            for (int ni = 0; ni < 2; ni++) bfr[ni] = *(const bf16x8*)&Bs[wn*32 + ni*16 + (lane & 15)][ko];
            #pragma unroll
            for (int mi = 0; mi < 2; mi++)
                #pragma unroll
                for (int ni = 0; ni < 2; ni++)
                    acc[mi][ni] = __builtin_amdgcn_mfma_f32_16x16x32_bf16(af[mi], bfr[ni], acc[mi][ni], 0, 0, 0);
        }
        __syncthreads();
    }
    #pragma unroll
    for (int mi = 0; mi < 2; mi++) {
        #pragma unroll
        for (int ni = 0; ni < 2; ni++) {
            int rbase = m0 + wm*32 + mi*16 + (lane >> 4)*4;
            int col   = n0 + wn*32 + ni*16 + (lane & 15);
            #pragma unroll
            for (int r = 0; r < 4; r++) {
                int row = rbase + r;
                float v = acc[mi][ni][r];
                if constexpr (EPI == 4) {
                    int b_ = row / NPATCH, p = row % NPATCH;
                    ((bf16*)Cv)[(size_t)(b_*NTOK + 1 + p)*EMB + col] =
                        __float2bfloat16(v + bias[col] + aux[(size_t)(1+p)*EMB + col]);
                } else if constexpr (EPI == 5) {
                    int hd = row >> 6, d = row & 63;
                    int bb = col / NTOK, t = col - bb*NTOK;
                    ((bf16*)Cv)[((size_t)((bb*3 + hd)*64 + d))*KPV + t] = __float2bfloat16(v);
                } else {
                    if constexpr (EPI == 1) v += bias[col]*bias_scale;
                    if constexpr (EPI == 2) v = ((float*)Cv)[(size_t)row*ldc + col] + v + bias[col];
                    if constexpr (EPI == 3) { v += bias[col]; v = 0.5f*v*(1.0f + erff(v*0.70710678118654752f)); }
                    if constexpr (OBF) ((bf16*)Cv)[(size_t)row*ldc + col] = __float2bfloat16(v);
                    else               ((float*)Cv)[(size_t)row*ldc + col] = v;
                }
            }
        }
    }
}

// ---------------------------------------------------------------- SAT per-sample rows (fp32, tiny)
__global__ __launch_bounds__(256) void sat_rows_kernel(
    const float* __restrict__ eleva, const float* __restrict__ eleva_var,
    const float* __restrict__ wq, const float* __restrict__ bq,
    const float* __restrict__ wk, const float* __restrict__ bk,
    const float* __restrict__ wv, const float* __restrict__ bv,
    const int* __restrict__ idx, float* __restrict__ proj, float* __restrict__ sconst)
{
    int s = blockIdx.x;
    __shared__ float ev[2][EMB];
    __shared__ float pr[6][SAT_D];
    int t = threadIdx.x;
    for (int i = t; i < 2*EMB; i += 256) {
        if (i < EMB) ev[0][i] = eleva[(size_t)idx[s]*EMB + i];
        else         ev[1][i-EMB] = eleva_var[(size_t)idx[16+s]*EMB + (i-EMB)];
    }
    __syncthreads();
    for (int j = 0; j < 6; j++) {
        const float* vec = ev[(j >= 3) ? 1 : 0];
        const float* Wm = (j%3 == 0) ? wq : ((j%3 == 1) ? wk : wv);
        const float* bm = (j%3 == 0) ? bq : ((j%3 == 1) ? bk : bv);
        float accv = bm[t];
        for (int k = 0; k < EMB; k++) accv += vec[k]*Wm[(size_t)k*SAT_D + t];
        pr[j][t] = accv;
        proj[((size_t)s*6 + j)*SAT_D + t] = accv;
    }
    __syncthreads();
    if (t < 32) {
        int h = t >> 2, c = t & 3;
        const float* qv = pr[(c < 2) ? 0 : 3];
        const float* kv = pr[((c & 1) == 0) ? 1 : 4];
        float d = 0.f;
        for (int x = 0; x < SAT_DK; x++) d += qv[h*32+x]*kv[h*32+x];
        sconst[((size_t)s*8 + h)*4 + c] = d * 0.17677669529663687f;
    }
}

// ---------------------------------------------------------------- SAT main (per token, bf16 io)
__global__ __launch_bounds__(256) void sat_attn_kernel(
    const bf16* __restrict__ qkv0, const float* __restrict__ proj,
    const float* __restrict__ sconst, bf16* __restrict__ osum)
{
    int b = blockIdx.x;
    int s = b & 15;
    __shared__ float pr[6][SAT_D];
    __shared__ float sc[8][4];
    for (int i = threadIdx.x; i < 6*SAT_D; i += 256) pr[i >> 8][i & 255] = proj[(size_t)s*6*SAT_D + i];
    if (threadIdx.x < 32) sc[threadIdx.x >> 2][threadIdx.x & 3] = sconst[(size_t)s*32 + threadIdx.x];
    __syncthreads();
    int t = threadIdx.x;
    if (t >= NTOK) return;
    size_t m = (size_t)b*NTOK + t;
    const ushort* q0 = (const ushort*)(qkv0 + m*768);
    const ushort* k0 = q0 + 256;
    const ushort* v0 = q0 + 512;
    const float inv = 0.17677669529663687f;
    for (int h = 0; h < SAT_H; h++) {
        int d0 = h*32;
        float S00=0,S01=0,S02=0,S10=0,S20=0;
        #pragma unroll 8
        for (int d = 0; d < 32; d++) {
            float qv = bf2f(q0[d0+d]), kv = bf2f(k0[d0+d]);
            S00 += qv*kv;
            S01 += qv*pr[1][d0+d];
            S02 += qv*pr[4][d0+d];
            S10 += pr[0][d0+d]*kv;
            S20 += pr[3][d0+d]*kv;
        }
        S00*=inv; S01*=inv; S02*=inv; S10*=inv; S20*=inv;
        float al=0.f, be=0.f, ga=0.f;
        {
            float mx = fmaxf(S00, fmaxf(S01, S02));
            float e0 = expf(S00-mx), e1 = expf(S01-mx), e2 = expf(S02-mx);
            float is = 1.0f/(e0+e1+e2); al += e0*is; be += e1*is; ga += e2*is;
        }
        {
            float a1 = sc[h][0], a2 = sc[h][1];
            float mx = fmaxf(S10, fmaxf(a1, a2));
            float e0 = expf(S10-mx), e1 = expf(a1-mx), e2 = expf(a2-mx);
            float is = 1.0f/(e0+e1+e2); al += e0*is; be += e1*is; ga += e2*is;
        }
        {
            float a1 = sc[h][2], a2 = sc[h][3];
            float mx = fmaxf(S20, fmaxf(a1, a2));
            float e0 = expf(S20-mx), e1 = expf(a1-mx), e2 = expf(a2-mx);
            float is = 1.0f/(e0+e1+e2); al += e0*is; be += e1*is; ga += e2*is;
        }
        #pragma unroll 8
        for (int d = 0; d < 32; d++)
            osum[m*SAT_D + d0 + d] = __float2bfloat16(al*bf2f(v0[d0+d]) + be*pr[2][d0+d] + ga*pr[5][d0+d]);
    }
}

// ---------------------------------------------------------------- ViT attention: full MFMA
// qkv: [M_TOK][384] = Q|K bf16.  vT: [(b*3+hd)*64 + d][KPV] bf16 (cols>=197 are don't-care).
// Grid 768 = 4 qgroups x 3 heads x 64 crops (XCD-chunked). 4 waves; wave w owns q-tile
// qstart(qg)+w (groups of {4,3,3,3} of the 13 16-query tiles).
// S^T tile = mfma(A=K, B=Q) -> lane-local softmax over keys -> P to LDS bf16 -> O = mfma(P, V^T).
__global__ __launch_bounds__(256) void vit_attn_mfma(
    const bf16* __restrict__ qkv, const bf16* __restrict__ vT, bf16* __restrict__ hout)
{
    __shared__ ushort Ks[208*72];        // row stride 72 bf16 (144 B)
    __shared__ ushort Vt[64*KPV];        // row stride 232 bf16 (464 B)
    __shared__ ushort Pl[4][16*KPV];

    int u = (blockIdx.x & 7)*96 + (blockIdx.x >> 3);   // XCD-chunked: 8 crops per XCD
    int qg = u & 3, hd = (u >> 2) % 3, b = u / 12;
    int tid = threadIdx.x;
    size_t rowQ = (size_t)b*NTOK;

    // stage K rows 0..207 (raw bf16 copy; rows >=197 zeroed)
    for (int i = tid; i < 208*8; i += 256) {
        int k = i >> 3, c = i & 7;
        uint4 v = make_uint4(0u,0u,0u,0u);
        if (k < NTOK) v = *(const uint4*)(qkv + (rowQ + k)*384 + 192 + hd*64 + c*8);
        *(uint4*)&Ks[(size_t)k*72 + c*8] = v;
    }
    // stage V^T: linear copy 64*KPV bf16 = 1856 uint4
    {
        const uint4* vsrc = (const uint4*)(vT + (size_t)((b*3 + hd)*64)*KPV);
        uint4* vdst = (uint4*)Vt;
        for (int i = tid; i < 64*KPV/8; i += 256) vdst[i] = vsrc[i];
    }
    __syncthreads();

    int wave = tid >> 6, lane = tid & 63;
    int qstart = (13*qg + 3) >> 2;                  // {0,4,7,10}
    int qcnt   = ((13*(qg+1) + 3) >> 2) - qstart;   // {4,3,3,3}
    if (wave >= qcnt) return;
    int q0 = (qstart + wave)*16;
    int qcol = lane & 15, g = lane >> 4;

    // Q fragments (B-operand): lane&15 = q, k-range = g*8 (+32)
    bf16x8 qf[2] = {};
    if (q0 + qcol < NTOK) {
        const bf16* qp = qkv + (rowQ + q0 + qcol)*384 + hd*64 + g*8;
        qf[0] = *(const bf16x8*)qp;
        qf[1] = *(const bf16x8*)(qp + 32);
    }

    // S^T: 13 key-tiles; lane holds S^T[key=16t+4g+r][q=qcol]
    f32x4 st[13] = {};
    #pragma unroll
    for (int t = 0; t < 13; t++) {
        const ushort* krow = &Ks[(size_t)(16*t + qcol)*72];
        bf16x8 a0 = *(const bf16x8*)(krow + g*8);
        bf16x8 a1 = *(const bf16x8*)(krow + 32 + g*8);
        st[t] = __builtin_amdgcn_mfma_f32_16x16x32_bf16(a0, qf[0], st[t], 0, 0, 0);
        st[t] = __builtin_amdgcn_mfma_f32_16x16x32_bf16(a1, qf[1], st[t], 0, 0, 0);
    }

    // softmax over keys (column q is lane-local across 4 lane-groups)
    const float scale = 0.125f;
    float mx = -1e30f;
    #pragma unroll
    for (int t = 0; t < 13; t++)
        #pragma unroll
        for (int r = 0; r < 4; r++) {
            int key = 16*t + 4*g + r;
            float s = st[t][r]*scale;
            st[t][r] = s;
            if (key < NTOK) mx = fmaxf(mx, s);
        }
    mx = fmaxf(mx, __shfl_xor(mx, 16));
    mx = fmaxf(mx, __shfl_xor(mx, 32));
    float sum = 0.f;
    #pragma unroll
    for (int t = 0; t < 13; t++)
        #pragma unroll
        for (int r = 0; r < 4; r++) {
            int key = 16*t + 4*g + r;
            float e = (key < NTOK) ? __expf(st[t][r] - mx) : 0.f;
            st[t][r] = e; sum += e;
        }
    sum += __shfl_xor(sum, 16);
    sum += __shfl_xor(sum, 32);
    float isv = 1.f/sum;

    // P -> LDS bf16 [q][key], zero pad keys 208..223
    ushort* P = Pl[wave];
    #pragma unroll
    for (int t = 0; t < 13; t++)
        #pragma unroll
        for (int r = 0; r < 4; r++)
            P[(size_t)qcol*KPV + 16*t + 4*g + r] = f2bf(st[t][r]*isv);
    #pragma unroll
    for (int r = 0; r < 4; r++)
        P[(size_t)qcol*KPV + 208 + 4*g + r] = 0;

    // O = P @ V^T : A = P (m=q), B = Vt (n=d); keys 0..223 in 7 k-steps
    f32x4 oacc[4] = {};
    #pragma unroll
    for (int ks = 0; ks < 7; ks++) {
        bf16x8 pf = *(const bf16x8*)&P[(size_t)qcol*KPV + ks*32 + g*8];
        #pragma unroll
        for (int dt = 0; dt < 4; dt++) {
            bf16x8 vf = *(const bf16x8*)&Vt[(size_t)(dt*16 + qcol)*KPV + ks*32 + g*8];
            oacc[dt] = __builtin_amdgcn_mfma_f32_16x16x32_bf16(pf, vf, oacc[dt], 0, 0, 0);
        }
    }

    // store O rows q=4g+r, cols hd*64 + dt*16 + qcol
    int nq = NTOK - q0; if (nq > 16) nq = 16;
    #pragma unroll
    for (int dt = 0; dt < 4; dt++)
        #pragma unroll
        for (int r = 0; r < 4; r++) {
            int q = 4*g + r;
            if (q < nq)
                hout[(rowQ + q0 + q)*EMB + hd*64 + dt*16 + qcol] = __float2bfloat16(oacc[dt][r]);
        }
}

// ---------------------------------------------------------------- LayerNorm fp32 -> bf16, 4 rows/block
__global__ __launch_bounds__(256) void ln_kernel(const float* __restrict__ in,
    const float* __restrict__ w, const float* __restrict__ b_, bf16* __restrict__ out, int nrows)
{
    int r = blockIdx.x*4 + (threadIdx.x >> 6);
    int lane = threadIdx.x & 63;
    if (r >= nrows) return;
    const float* x = in + (size_t)r*EMB;
    float x0 = x[lane], x1 = x[lane+64], x2 = x[lane+128];
    float s = x0+x1+x2;
    for (int o = 32; o > 0; o >>= 1) s += __shfl_xor(s, o);
    float mu = s * (1.0f/EMB);
    float d0 = x0-mu, d1 = x1-mu, d2 = x2-mu;
    float ss = d0*d0 + d1*d1 + d2*d2;
    for (int o = 32; o > 0; o >>= 1) ss += __shfl_xor(ss, o);
    float rs = rsqrtf(ss*(1.0f/EMB) + 1e-5f);
    bf16* y = out + (size_t)r*EMB;
    y[lane]     = __float2bfloat16(d0*rs*w[lane]     + b_[lane]);
    y[lane+64]  = __float2bfloat16(d1*rs*w[lane+64]  + b_[lane+64]);
    y[lane+128] = __float2bfloat16(d2*rs*w[lane+128] + b_[lane+128]);
}

// ---------------------------------------------------------------- final LN on t=0 rows only
__global__ __launch_bounds__(64) void final_ln_kernel(const float* __restrict__ tok,
    const float* __restrict__ w, const float* __restrict__ b_, float* __restrict__ out)
{
    int b = blockIdx.x, lane = threadIdx.x;
    const float* x = tok + (size_t)b*NTOK*EMB;
    float x0 = x[lane], x1 = x[lane+64], x2 = x[lane+128];
    float s = x0+x1+x2;
    for (int o = 32; o > 0; o >>= 1) s += __shfl_xor(s, o);
    float mu = s * (1.0f/EMB);
    float d0 = x0-mu, d1 = x1-mu, d2 = x2-mu;
    float ss = d0*d0 + d1*d1 + d2*d2;
    for (int o = 32; o > 0; o >>= 1) ss += __shfl_xor(ss, o);
    float rs = rsqrtf(ss*(1.0f/EMB) + 1e-5f);
    out[(size_t)b*EMB + lane]     = d0*rs*w[lane]     + b_[lane];
    out[(size_t)b*EMB + lane+64]  = d1*rs*w[lane+64]  + b_[lane+64];
    out[(size_t)b*EMB + lane+128] = d2*rs*w[lane+128] + b_[lane+128];
}

// ---------------------------------------------------------------- launch
extern "C" void kernel_launch(void* const* d_in, const int* in_sizes, int n_in,
                              void* d_out, int out_size, void* d_ws, size_t ws_size,
                              hipStream_t stream)
{
    const float* x          = (const float*)d_in[0];
    const float* xg         = (const float*)d_in[1];
    const float* per_li     = (const float*)d_in[2];
    const float* per_li_var = (const float*)d_in[3];
    const float* patch_w    = (const float*)d_in[4];
    const float* patch_b    = (const float*)d_in[5];
    const float* cls_token  = (const float*)d_in[6];
    const float* pos_embed  = (const float*)d_in[7];
    const float* eleva      = (const float*)d_in[8];
    const float* eleva_var  = (const float*)d_in[9];
    const float* sat_wq     = (const float*)d_in[10];
    const float* sat_bq     = (const float*)d_in[11];
    const float* sat_wk     = (const float*)d_in[12];
    const float* sat_bk     = (const float*)d_in[13];
    const float* sat_wv     = (const float*)d_in[14];
    const float* sat_bv     = (const float*)d_in[15];
    const float* sat_wo     = (const float*)d_in[16];
    const float* sat_bo     = (const float*)d_in[17];
    const float* ln1_w      = (const float*)d_in[18];
    const float* ln1_b      = (const float*)d_in[19];
    const float* qkv_w      = (const float*)d_in[20];
    const float* proj_w     = (const float*)d_in[21];
    const float* proj_b     = (const float*)d_in[22];
    const float* ln2_w      = (const float*)d_in[23];
    const float* ln2_b      = (const float*)d_in[24];
    const float* fc1_w      = (const float*)d_in[25];
    const float* fc1_b      = (const float*)d_in[26];
    const float* fc2_w      = (const float*)d_in[27];
    const float* fc2_b      = (const float*)d_in[28];
    const float* lnf_w      = (const float*)d_in[29];
    const float* lnf_b      = (const float*)d_in[30];
    float* out = (float*)d_out;

    char* p = (char*)d_ws;
    float* tokf = (float*)p;                 p += (size_t)M_TOK*EMB*4;
    bf16* hb    = (bf16*)p;                  p += (size_t)M_TOK*EMB*2;
    bf16* tokb  = (bf16*)p;                  p += (size_t)M_TOK*EMB*2;
    bf16* qkvb  = (bf16*)p;                  p += (size_t)M_TOK*768*2;
    bf16* osum  = (bf16*)p;                  p += (size_t)M_TOK*SAT_D*2;
    bf16* vTb   = (bf16*)p;                  p += (size_t)NB*3*64*KPV*2;
    bf16* qkv_wt  = (bf16*)p;                p += (size_t)DEPTH*576*EMB*2;
    bf16* proj_wt = (bf16*)p;                p += (size_t)DEPTH*EMB*EMB*2;
    bf16* fc1_wt  = (bf16*)p;                p += (size_t)DEPTH*MLPD*EMB*2;
    bf16* fc2_wt  = (bf16*)p;                p += (size_t)DEPTH*EMB*MLPD*2;
    bf16* patch_wb= (bf16*)p;                p += (size_t)EMB*768*2;
    bf16* sat_wqt = (bf16*)p;                p += (size_t)SAT_D*EMB*2;
    bf16* sat_wkt = (bf16*)p;                p += (size_t)SAT_D*EMB*2;
    bf16* sat_wvt = (bf16*)p;                p += (size_t)SAT_D*EMB*2;
    bf16* sat_wot = (bf16*)p;                p += (size_t)EMB*SAT_D*2;
    float* projb  = (float*)p;               p += 16*6*SAT_D*4;
    float* sconst = (float*)p;               p += 16*32*4;
    int*   idxb   = (int*)p;

    // ---- weight prep (bf16, [N][K] transposed) ----
    transpose_cast_kernel<<<dim3(576/32, EMB/32, DEPTH), 256, 0, stream>>>(qkv_w,  qkv_wt,  EMB, 576);
    transpose_cast_kernel<<<dim3(EMB/32, EMB/32, DEPTH), 256, 0, stream>>>(proj_w, proj_wt, EMB, EMB);
    transpose_cast_kernel<<<dim3(MLPD/32, EMB/32, DEPTH), 256, 0, stream>>>(fc1_w, fc1_wt,  EMB, MLPD);
    transpose_cast_kernel<<<dim3(EMB/32, MLPD/32, DEPTH), 256, 0, stream>>>(fc2_w, fc2_wt,  MLPD, EMB);
    transpose_cast_kernel<<<dim3(SAT_D/32, EMB/32, 1), 256, 0, stream>>>(sat_wq, sat_wqt, EMB, SAT_D);
    transpose_cast_kernel<<<dim3(SAT_D/32, EMB/32, 1), 256, 0, stream>>>(sat_wk, sat_wkt, EMB, SAT_D);
    transpose_cast_kernel<<<dim3(SAT_D/32, EMB/32, 1), 256, 0, stream>>>(sat_wv, sat_wvt, EMB, SAT_D);
    transpose_cast_kernel<<<dim3(EMB/32, SAT_D/32, 1), 256, 0, stream>>>(sat_wo, sat_wot, SAT_D, EMB);
    cast_kernel<<<(EMB*768 + 255)/256, 256, 0, stream>>>(patch_w, patch_wb, EMB*768);

    // ---- elevation stats ----
    stats_kernel<<<16, 256, 0, stream>>>(xg, per_li, per_li_var, idxb);
    // ---- patch embed ----
    im2col_kernel<<<(M_PATCH*768 + 255)/256, 256, 0, stream>>>(x, qkvb);
    mfma_gemm<4,true><<<dim3(EMB/64, M_PATCH/64), 256, 0, stream>>>(
        qkvb, patch_wb, patch_b, pos_embed, tokb, M_PATCH, EMB, 768, EMB, 1.0f);
    cls_kernel<<<(NB*EMB + 255)/256, 256, 0, stream>>>(cls_token, pos_embed, tokb);
    // ---- SAT ----
    sat_rows_kernel<<<16, 256, 0, stream>>>(eleva, eleva_var, sat_wq, sat_bq, sat_wk, sat_bk,
                                            sat_wv, sat_bv, idxb, projb, sconst);
    mfma_gemm<1,true><<<dim3(SAT_D/64, M_TOK/64), 256, 0, stream>>>(
        tokb, sat_wqt, sat_bq, nullptr, qkvb + 0,   M_TOK, SAT_D, EMB, 768, 1.0f);
    mfma_gemm<1,true><<<dim3(SAT_D/64, M_TOK/64), 256, 0, stream>>>(
        tokb, sat_wkt, sat_bk, nullptr, qkvb + 256, M_TOK, SAT_D, EMB, 768, 1.0f);
    mfma_gemm<1,true><<<dim3(SAT_D/64, M_TOK/64), 256, 0, stream>>>(
        tokb, sat_wvt, sat_bv, nullptr, qkvb + 512, M_TOK, SAT_D, EMB, 768, 1.0f);
    sat_attn_kernel<<<NB, 256, 0, stream>>>(qkvb, projb, sconst, osum);
    mfma_gemm<1,false><<<dim3(EMB/64, M_TOK/64), 256, 0, stream>>>(
        osum, sat_wot, sat_bo, nullptr, tokf, M_TOK, EMB, SAT_D, EMB, 3.0f);
    // ---- ViT blocks ----
    for (int i = 0; i < DEPTH; i++) {
        ln_kernel<<<M_TOK/4, 256, 0, stream>>>(tokf, ln1_w + i*EMB, ln1_b + i*EMB, hb, M_TOK);
        // Q|K projection: [M][384]
        mfma_gemm<0,true><<<dim3(384/64, M_TOK/64), 256, 0, stream>>>(
            hb, qkv_wt + (size_t)i*576*EMB, nullptr, nullptr, qkvb, M_TOK, 384, EMB, 384, 1.0f);
        // V projection, transposed scatter: M = 192 d-dims, N = 12608 toks
        mfma_gemm<5,true><<<dim3(M_TOK/64, EMB/64), 256, 0, stream>>>(
            qkv_wt + ((size_t)i*576 + 384)*EMB, hb, nullptr, nullptr, vTb, EMB, M_TOK, EMB, 0, 1.0f);
        vit_attn_mfma<<<768, 256, 0, stream>>>(qkvb, vTb, hb);
        mfma_gemm<2,false><<<dim3(EMB/64, M_TOK/64), 256, 0, stream>>>(
            hb, proj_wt + (size_t)i*EMB*EMB, proj_b + i*EMB, nullptr, tokf, M_TOK, EMB, EMB, EMB, 1.0f);
        ln_kernel<<<M_TOK/4, 256, 0, stream>>>(tokf, ln2_w + i*EMB, ln2_b + i*EMB, hb, M_TOK);
        mfma_gemm<3,true><<<dim3(MLPD/64, M_TOK/64), 256, 0, stream>>>(
            hb, fc1_wt + (size_t)i*MLPD*EMB, fc1_b + i*MLPD, nullptr, qkvb, M_TOK, MLPD, EMB, MLPD, 1.0f);
        mfma_gemm<2,false><<<dim3(EMB/64, M_TOK/64), 256, 0, stream>>>(
            qkvb, fc2_wt + (size_t)i*EMB*MLPD, fc2_b + i*EMB, nullptr, tokf, M_TOK, EMB, MLPD, EMB, 1.0f);
    }
    final_ln_kernel<<<NB, 64, 0, stream>>>(tokf, lnf_w, lnf_b, out);
}